// Round 1
// baseline (7507.382 us; speedup 1.0000x reference)
//
#include <hip/hip_runtime.h>
#include <math.h>

// CapsNet forward, fp32 correctness-first implementation.
// Shapes: B=256, conv1: (1->256,k9) 28x28->20x20, pconv: (256->256,k9,s2) ->6x6
// caps: 1152 in-caps x 8, 10 out-caps x 16, routing 3+1 iters, decoder 160->512->1024->784.

// ---------------- conv1: x(256,1,28,28) * w(256,81) -> out(256,256,20,20) ----------------
__global__ __launch_bounds__(256, 4) void conv1_kernel(
    const float* __restrict__ x, const float* __restrict__ w,
    const float* __restrict__ bias, float* __restrict__ out)
{
    __shared__ float xs[784];        // 28x28 input plane
    __shared__ float wl[64 * 81];    // [co_local][k]
    int t = threadIdx.x;
    int n = blockIdx.x;
    int cot = blockIdx.y;            // 4 tiles of 64 co

    for (int j = t; j < 784; j += 256) xs[j] = x[n * 784 + j];
    for (int j = t; j < 64 * 81; j += 256) {
        int co_s = j / 81, k = j % 81;
        wl[co_s * 81 + k] = w[(cot * 64 + co_s) * 81 + k];
    }
    __syncthreads();

    int co_l = t & 63, slot = t >> 6;   // wave = one row-slot, 64 co per wave (x reads broadcast)
    int co = cot * 64 + co_l;
    float bv = bias[co];
    for (int r5 = 0; r5 < 5; ++r5) {
        int py = slot * 5 + r5;          // output row 0..19
        float acc[20];
        #pragma unroll
        for (int i = 0; i < 20; i++) acc[i] = bv;
        #pragma unroll
        for (int ky = 0; ky < 9; ++ky) {
            float xr[28];
            const float4* rowp = (const float4*)&xs[(py + ky) * 28];  // 112B rows: 16B aligned
            #pragma unroll
            for (int q = 0; q < 7; q++) {
                float4 v4 = rowp[q];
                xr[4*q] = v4.x; xr[4*q+1] = v4.y; xr[4*q+2] = v4.z; xr[4*q+3] = v4.w;
            }
            #pragma unroll
            for (int kx = 0; kx < 9; ++kx) {
                float wv = wl[co_l * 81 + ky * 9 + kx];   // stride 81 -> 2-way, free
                #pragma unroll
                for (int px = 0; px < 20; ++px) acc[px] += wv * xr[px + kx];
            }
        }
        float* op = &out[(size_t)n * 102400 + (size_t)co * 400 + py * 20];
        #pragma unroll
        for (int q = 0; q < 5; q++)
            ((float4*)op)[q] = make_float4(acc[4*q], acc[4*q+1], acc[4*q+2], acc[4*q+3]);
    }
}

// ---------------- pconv: h(256,256,20,20) * w(256,256,81) stride2 -> (256,256,6,6) ----------------
// Block: 4 waves = 4 batch-planes, 64 co per lane. ci split in halves (blockIdx.z) for occupancy.
__global__ __launch_bounds__(256, 2) void pconv_kernel(
    const float* __restrict__ h, const float* __restrict__ w,
    const float* __restrict__ bias,
    float* __restrict__ out0, float* __restrict__ out1)
{
    __shared__ float xs[4 * 400];     // 4 input planes (one per wave)
    __shared__ float wl[81 * 65];     // [k][co] padded 65 -> conflict-free
    int t = threadIdx.x;
    int wid = t >> 6, lane = t & 63;
    int ng = blockIdx.x;              // 64 groups of 4 batches
    int cot = blockIdx.y;             // 4 tiles of 64 co
    int half = blockIdx.z;            // ci half
    int n = ng * 4 + wid;
    int co = cot * 64 + lane;

    float acc[36];
    #pragma unroll
    for (int i = 0; i < 36; i++) acc[i] = 0.f;

    int ci0 = half * 128;
    for (int ci = ci0; ci < ci0 + 128; ++ci) {
        __syncthreads();
        for (int j = lane; j < 400; j += 64)
            xs[wid * 400 + j] = h[(size_t)n * 102400 + (size_t)ci * 400 + j];
        for (int idx = t; idx < 64 * 81; idx += 256) {
            int co_s = idx / 81, k = idx % 81;    // coalesced global read along k
            wl[k * 65 + co_s] = w[((size_t)(cot * 64 + co_s) * 256 + ci) * 81 + k];
        }
        __syncthreads();

        float wreg[81];
        #pragma unroll
        for (int k = 0; k < 81; k++) wreg[k] = wl[k * 65 + lane];

        #pragma unroll
        for (int r = 0; r < 20; ++r) {            // each x row read once per ci
            float xr[20];
            const float4* rp = (const float4*)&xs[wid * 400 + r * 20];
            #pragma unroll
            for (int q = 0; q < 5; q++) {
                float4 v4 = rp[q];
                xr[4*q] = v4.x; xr[4*q+1] = v4.y; xr[4*q+2] = v4.z; xr[4*q+3] = v4.w;
            }
            #pragma unroll
            for (int oy = 0; oy < 6; ++oy) {
                int ky = r - 2 * oy;               // folds at compile time per (r,oy)
                if (ky >= 0 && ky < 9) {
                    #pragma unroll
                    for (int kx = 0; kx < 9; ++kx) {
                        float wvv = wreg[ky * 9 + kx];
                        #pragma unroll
                        for (int ox = 0; ox < 6; ++ox)
                            acc[oy * 6 + ox] += wvv * xr[2 * ox + kx];
                    }
                }
            }
        }
    }
    float* outp = (half == 0) ? out0 : out1;
    float bv = (half == 0) ? bias[co] : 0.f;      // bias added exactly once
    #pragma unroll
    for (int p = 0; p < 36; p++)
        outp[(size_t)n * 9216 + (size_t)co * 36 + p] = acc[p] + bv;
}

// ---------------- combine halves + squash over 8-dim capsules ----------------
__global__ __launch_bounds__(256) void squash_u_kernel(
    const float* __restrict__ p0, const float* __restrict__ p1, float* __restrict__ u)
{
    int cap = blockIdx.x * 256 + threadIdx.x;   // 0..294911
    const float4* a0 = (const float4*)(p0 + (size_t)cap * 8);
    const float4* a1 = (const float4*)(p1 + (size_t)cap * 8);
    float4 x0 = a0[0], x1 = a0[1], y0 = a1[0], y1 = a1[1];
    float z[8] = {x0.x + y0.x, x0.y + y0.y, x0.z + y0.z, x0.w + y0.w,
                  x1.x + y1.x, x1.y + y1.y, x1.z + y1.z, x1.w + y1.w};
    float n2 = 0.f;
    #pragma unroll
    for (int k = 0; k < 8; k++) n2 += z[k] * z[k];
    float sc = sqrtf(n2) / (1.0f + n2);          // squash(x) = x*|x|/(1+|x|^2)
    float4* op = (float4*)(u + (size_t)cap * 8);
    op[0] = make_float4(z[0]*sc, z[1]*sc, z[2]*sc, z[3]*sc);
    op[1] = make_float4(z[4]*sc, z[5]*sc, z[6]*sc, z[7]*sc);
}

// ---------------- softmax over j=10 ----------------
__global__ void softmax_c_kernel(const float* __restrict__ b, float* __restrict__ c)
{
    int i = blockIdx.x * 256 + threadIdx.x;
    if (i >= 1152) return;
    float e[10], m = -1e30f;
    #pragma unroll
    for (int j = 0; j < 10; j++) { e[j] = b[i * 10 + j]; m = fmaxf(m, e[j]); }
    float sum = 0.f;
    #pragma unroll
    for (int j = 0; j < 10; j++) { e[j] = expf(e[j] - m); sum += e[j]; }
    float inv = 1.f / sum;
    #pragma unroll
    for (int j = 0; j < 10; j++) c[i * 10 + j] = e[j] * inv;
}

// ---------------- s[n,j,a] = sum_i c[i,j] * dot8(W[i,j,a,:], u[n,i,:]) ----------------
// grid (j=10, ntile=16, ihalf=2), block 256 = 16a x 16n. u_hat never materialized.
__global__ __launch_bounds__(256) void s_kernel(
    const float* __restrict__ c, const float* __restrict__ u,
    const float* __restrict__ W, float* __restrict__ s0, float* __restrict__ s1)
{
    int t = threadIdx.x;
    int a = t & 15, n_l = t >> 4;
    int j = blockIdx.x;
    int n = blockIdx.y * 16 + n_l;
    float* sout = (blockIdx.z == 0) ? s0 : s1;
    int i0 = blockIdx.z * 576;
    float acc = 0.f;
    for (int i = i0; i < i0 + 576; ++i) {
        float cij = c[i * 10 + j];                                  // block-uniform -> s_load
        const float4* wp = (const float4*)&W[(((size_t)i * 10 + j) * 16 + a) * 8];
        float4 w0 = wp[0], w1 = wp[1];
        const float4* up = (const float4*)&u[(size_t)n * 9216 + (size_t)i * 8];
        float4 q0 = up[0], q1 = up[1];
        float d = w0.x*q0.x + w0.y*q0.y + w0.z*q0.z + w0.w*q0.w
                + w1.x*q1.x + w1.y*q1.y + w1.z*q1.z + w1.w*q1.w;
        acc += cij * d;
    }
    sout[((size_t)n * 10 + j) * 16 + a] = acc;
}

// ---------------- v = squash(s0+s1) over 16-dim; optionally emit to d_out ----------------
__global__ void squash_v_kernel(const float* __restrict__ s0, const float* __restrict__ s1,
                                float* __restrict__ v, float* __restrict__ vout)
{
    int idx = blockIdx.x * 256 + threadIdx.x;    // (n*10+j) in 0..2559
    if (idx >= 2560) return;
    float xv[16], n2 = 0.f;
    #pragma unroll
    for (int a = 0; a < 16; a++) {
        xv[a] = s0[idx * 16 + a] + s1[idx * 16 + a];
        n2 += xv[a] * xv[a];
    }
    float sc = sqrtf(n2) / (1.0f + n2);
    #pragma unroll
    for (int a = 0; a < 16; a++) {
        float y = xv[a] * sc;
        v[idx * 16 + a] = y;
        if (vout) vout[idx * 16 + a] = y;
    }
}

// ---------------- b[i,j] += sum_{a,b} W[i,j,a,b] * (sum_n u[n,i,b]*v[n,j,a]) ----------------
// grid 1152 (=i), 160 active threads = (j,a).
__global__ __launch_bounds__(192) void bupd_kernel(
    const float* __restrict__ u, const float* __restrict__ v,
    const float* __restrict__ W, float* __restrict__ b)
{
    int i = blockIdx.x;
    int t = threadIdx.x;
    if (t >= 160) return;
    int j = t >> 4, a = t & 15;
    float g[8];
    #pragma unroll
    for (int k = 0; k < 8; k++) g[k] = 0.f;
    for (int n = 0; n < 256; ++n) {
        float vv = v[n * 160 + t];                                  // coalesced
        const float4* up = (const float4*)&u[(size_t)n * 9216 + (size_t)i * 8];  // uniform -> s_load
        float4 q0 = up[0], q1 = up[1];
        g[0] += q0.x * vv; g[1] += q0.y * vv; g[2] += q0.z * vv; g[3] += q0.w * vv;
        g[4] += q1.x * vv; g[5] += q1.y * vv; g[6] += q1.z * vv; g[7] += q1.w * vv;
    }
    const float4* wp = (const float4*)&W[(((size_t)i * 10 + j) * 16 + a) * 8];
    float4 w0 = wp[0], w1 = wp[1];
    float p = w0.x*g[0] + w0.y*g[1] + w0.z*g[2] + w0.w*g[3]
            + w1.x*g[4] + w1.y*g[5] + w1.z*g[6] + w1.w*g[7];
    p += __shfl_xor(p, 1);     // reduce over a (16-lane groups, xor stays in-group)
    p += __shfl_xor(p, 2);
    p += __shfl_xor(p, 4);
    p += __shfl_xor(p, 8);
    if (a == 0) b[i * 10 + j] += p;
}

// ---------------- argmax(|v|) + mask -> decoder input (256,160) ----------------
__global__ void mask_kernel(const float* __restrict__ v, float* __restrict__ out)
{
    int n = threadIdx.x;                         // one block of 256
    const float* vp = &v[n * 160];
    int best = 0; float bestv = -1.f;
    for (int j = 0; j < 10; j++) {
        float n2 = 0.f;
        #pragma unroll
        for (int a = 0; a < 16; a++) { float y = vp[j * 16 + a]; n2 += y * y; }
        float ln = sqrtf(n2);                    // match ref's norm-space tie behavior
        if (ln > bestv) { bestv = ln; best = j; }  // strict > keeps first max (jnp.argmax)
    }
    for (int j = 0; j < 10; j++)
        for (int a = 0; a < 16; a++)
            out[n * 160 + j * 16 + a] = (j == best) ? vp[j * 16 + a] : 0.f;
}

// ---------------- decoder GEMM: out(256,O) = act(X(256,K) @ W(K,O) + bias) ----------------
// block covers 32 n x 256 o; thread = 8n x 4o. act: 0=relu, 1=sigmoid.
__global__ __launch_bounds__(256) void mlp_kernel(
    const float* __restrict__ X, const float* __restrict__ Wm,
    const float* __restrict__ bias, float* __restrict__ out,
    int K, int O, int act)
{
    __shared__ float XS[64 * 36];                // [k][n] padded to 36
    int t = threadIdx.x;
    int og = t & 63, ns = t >> 6;
    int n0 = blockIdx.x * 32;
    int o = blockIdx.y * 256 + og * 4;
    int o_c = min(o, O - 4);                     // clamped (O % 4 == 0 for all layers)
    float acc[8][4];
    #pragma unroll
    for (int s = 0; s < 8; s++)
        #pragma unroll
        for (int q = 0; q < 4; q++) acc[s][q] = 0.f;

    for (int kc = 0; kc < K; kc += 64) {
        int kn = min(64, K - kc);
        __syncthreads();
        for (int idx = t; idx < 2048; idx += 256) {
            int k_l = idx & 63, n_l = idx >> 6;
            XS[k_l * 36 + n_l] = (k_l < kn) ? X[(size_t)(n0 + n_l) * K + kc + k_l] : 0.f;
        }
        __syncthreads();
        for (int k = 0; k < kn; ++k) {
            float4 wv = *(const float4*)&Wm[(size_t)(kc + k) * O + o_c];
            float4 xa = *(const float4*)&XS[k * 36 + ns * 8];
            float4 xb = *(const float4*)&XS[k * 36 + ns * 8 + 4];
            float xs8[8] = {xa.x, xa.y, xa.z, xa.w, xb.x, xb.y, xb.z, xb.w};
            #pragma unroll
            for (int s = 0; s < 8; s++) {
                acc[s][0] += xs8[s] * wv.x;
                acc[s][1] += xs8[s] * wv.y;
                acc[s][2] += xs8[s] * wv.z;
                acc[s][3] += xs8[s] * wv.w;
            }
        }
    }
    if (o < O) {
        float4 bv = *(const float4*)&bias[o];
        #pragma unroll
        for (int s = 0; s < 8; s++) {
            float r[4] = {acc[s][0] + bv.x, acc[s][1] + bv.y, acc[s][2] + bv.z, acc[s][3] + bv.w};
            #pragma unroll
            for (int q = 0; q < 4; q++)
                r[q] = (act == 0) ? fmaxf(r[q], 0.f) : (1.f / (1.f + expf(-r[q])));
            *(float4*)&out[(size_t)(n0 + ns * 8 + s) * O + o] = make_float4(r[0], r[1], r[2], r[3]);
        }
    }
}

extern "C" void kernel_launch(void* const* d_in, const int* in_sizes, int n_in,
                              void* d_out, int out_size, void* d_ws, size_t ws_size,
                              hipStream_t stream)
{
    const float* x       = (const float*)d_in[0];
    const float* conv1_w = (const float*)d_in[1];
    const float* conv1_b = (const float*)d_in[2];
    const float* pconv_w = (const float*)d_in[3];
    const float* pconv_b = (const float*)d_in[4];
    const float* W_caps  = (const float*)d_in[5];
    const float* dec_w1  = (const float*)d_in[6];
    const float* dec_b1  = (const float*)d_in[7];
    const float* dec_w2  = (const float*)d_in[8];
    const float* dec_b2  = (const float*)d_in[9];
    const float* dec_w3  = (const float*)d_in[10];
    const float* dec_b3  = (const float*)d_in[11];
    float* out = (float*)d_out;

    float* ws = (float*)d_ws;
    size_t off = 0;
    auto alloc = [&](size_t nf) { float* p = ws + off; off += (nf + 63) & ~(size_t)63; return p; };
    float* conv1_out = alloc(26214400);   // (256,256,20,20)
    float* part0     = alloc(2359296);    // pconv ci-half 0
    float* part1     = alloc(2359296);    // pconv ci-half 1
    float* u_in      = alloc(2359296);    // squashed (256,1152,8)
    float* bbuf      = alloc(11520);      // routing logits b (1152,10)
    float* cbuf      = alloc(11520);
    float* s0        = alloc(40960);      // s partials (i-halves)
    float* s1        = alloc(40960);
    float* vbuf      = alloc(40960);      // v (256,10,16)
    float* rin       = alloc(40960);      // masked decoder input (256,160)
    float* h1        = alloc(131072);
    float* h2        = alloc(262144);

    hipMemsetAsync(bbuf, 0, 11520 * sizeof(float), stream);

    conv1_kernel<<<dim3(256, 4), 256, 0, stream>>>(x, conv1_w, conv1_b, conv1_out);
    pconv_kernel<<<dim3(64, 4, 2), 256, 0, stream>>>(conv1_out, pconv_w, pconv_b, part0, part1);
    squash_u_kernel<<<1152, 256, 0, stream>>>(part0, part1, u_in);

    for (int r = 0; r < 4; ++r) {
        softmax_c_kernel<<<5, 256, 0, stream>>>(bbuf, cbuf);
        s_kernel<<<dim3(10, 16, 2), 256, 0, stream>>>(cbuf, u_in, W_caps, s0, s1);
        squash_v_kernel<<<10, 256, 0, stream>>>(s0, s1, vbuf, (r == 3) ? out : nullptr);
        if (r < 3) bupd_kernel<<<1152, 192, 0, stream>>>(u_in, vbuf, W_caps, bbuf);
    }

    mask_kernel<<<1, 256, 0, stream>>>(vbuf, rin);
    mlp_kernel<<<dim3(8, 2), 256, 0, stream>>>(rin, dec_w1, dec_b1, h1, 160, 512, 0);
    mlp_kernel<<<dim3(8, 4), 256, 0, stream>>>(h1, dec_w2, dec_b2, h2, 512, 1024, 0);
    mlp_kernel<<<dim3(8, 4), 256, 0, stream>>>(h2, dec_w3, dec_b3, out + 40960, 1024, 784, 1);
}

// Round 2
// 4504.314 us; speedup vs baseline: 1.6667x; 1.6667x over previous
//
#include <hip/hip_runtime.h>
#include <math.h>

// CapsNet forward, fp32. Round 2: de-spill pconv (2-chunk weight registers,
// uniform global x-row reads off the LDS pipe, ci quarters for occupancy).

// ---------------- conv1: x(256,1,28,28) * w(256,81) -> out(256,256,20,20) ----------------
__global__ __launch_bounds__(256, 4) void conv1_kernel(
    const float* __restrict__ x, const float* __restrict__ w,
    const float* __restrict__ bias, float* __restrict__ out)
{
    __shared__ float xs[784];        // 28x28 input plane
    __shared__ float wl[64 * 81];    // [co_local][k]
    int t = threadIdx.x;
    int n = blockIdx.x;
    int cot = blockIdx.y;            // 4 tiles of 64 co

    for (int j = t; j < 784; j += 256) xs[j] = x[n * 784 + j];
    for (int j = t; j < 64 * 81; j += 256) {
        int co_s = j / 81, k = j % 81;
        wl[co_s * 81 + k] = w[(cot * 64 + co_s) * 81 + k];
    }
    __syncthreads();

    int co_l = t & 63, slot = t >> 6;   // wave = one row-slot, 64 co per wave
    int co = cot * 64 + co_l;
    float bv = bias[co];
    for (int r5 = 0; r5 < 5; ++r5) {
        int py = slot * 5 + r5;          // output row 0..19
        float acc[20];
        #pragma unroll
        for (int i = 0; i < 20; i++) acc[i] = bv;
        #pragma unroll
        for (int ky = 0; ky < 9; ++ky) {
            float xr[28];
            const float4* rowp = (const float4*)&xs[(py + ky) * 28];
            #pragma unroll
            for (int q = 0; q < 7; q++) {
                float4 v4 = rowp[q];
                xr[4*q] = v4.x; xr[4*q+1] = v4.y; xr[4*q+2] = v4.z; xr[4*q+3] = v4.w;
            }
            #pragma unroll
            for (int kx = 0; kx < 9; ++kx) {
                float wv = wl[co_l * 81 + ky * 9 + kx];
                #pragma unroll
                for (int px = 0; px < 20; ++px) acc[px] += wv * xr[px + kx];
            }
        }
        float* op = &out[(size_t)n * 102400 + (size_t)co * 400 + py * 20];
        #pragma unroll
        for (int q = 0; q < 5; q++)
            ((float4*)op)[q] = make_float4(acc[4*q], acc[4*q+1], acc[4*q+2], acc[4*q+3]);
    }
}

// ---------------- pconv: h(256,256,20,20) * w(256,256,81) stride2 -> (256,256,6,6) ----------------
// Wave = one n-plane, 64 lanes = 64 co. Weights staged in LDS per ci, held in
// registers in two ky-chunks (<=45 live). x rows read from GLOBAL with a
// wave-uniform address (scalar/broadcast path -> off the LDS pipe).
template<int KY0, int KY1>
__device__ __forceinline__ void pconv_chunk(const float* __restrict__ hplane,
                                            const float* __restrict__ wl,
                                            int lane, float* __restrict__ acc)
{
    constexpr int NK = (KY1 - KY0 + 1) * 9;
    float wreg[NK];
    #pragma unroll
    for (int k = 0; k < NK; ++k) wreg[k] = wl[lane * 81 + KY0 * 9 + k];
    constexpr int RMAX = (10 + KY1 < 19) ? (10 + KY1) : 19;
    #pragma unroll
    for (int r = KY0; r <= RMAX; ++r) {
        float xr[20];
        #pragma unroll
        for (int q = 0; q < 5; ++q) {
            float4 v4 = *(const float4*)(hplane + r * 20 + q * 4);  // uniform addr
            xr[4*q+0] = v4.x; xr[4*q+1] = v4.y; xr[4*q+2] = v4.z; xr[4*q+3] = v4.w;
        }
        #pragma unroll
        for (int oy = 0; oy < 6; ++oy) {
            int ky = r - 2 * oy;                  // constant after unroll
            if (ky >= KY0 && ky <= KY1) {
                #pragma unroll
                for (int kx = 0; kx < 9; ++kx) {
                    float wv = wreg[(ky - KY0) * 9 + kx];
                    #pragma unroll
                    for (int ox = 0; ox < 6; ++ox)
                        acc[oy * 6 + ox] += wv * xr[2 * ox + kx];
                }
            }
        }
    }
}

__global__ __launch_bounds__(256, 4) void pconv_kernel(
    const float* __restrict__ h, const float* __restrict__ w,
    const float* __restrict__ bias, float* __restrict__ parts)
{
    __shared__ float wl[64 * 81];     // [co_local][81], identity layout
    int t = threadIdx.x;
    int lane = t & 63;
    int wid = __builtin_amdgcn_readfirstlane(t >> 6);  // force wave-uniform
    int ng = blockIdx.x;              // 64 groups of 4 batches
    int cot = blockIdx.y;             // 4 tiles of 64 co
    int q = blockIdx.z;               // ci quarter
    int n = ng * 4 + wid;
    int co = cot * 64 + lane;

    float acc[36];
    #pragma unroll
    for (int i = 0; i < 36; i++) acc[i] = 0.f;

    const float* hn = h + (size_t)n * 102400;
    const float* wt = w + (size_t)cot * 64 * 20736;   // + co_s*20736 + ci*81 + k
    int ci0 = q * 64;
    for (int ci = ci0; ci < ci0 + 64; ++ci) {
        __syncthreads();
        const float* wsrc = wt + (size_t)ci * 81;
        for (int idx = t; idx < 5184; idx += 256)
            wl[idx] = wsrc[(size_t)(idx / 81) * 20736 + (idx % 81)];
        __syncthreads();
        const float* hplane = hn + (size_t)ci * 400;
        pconv_chunk<0, 3>(hplane, wl, lane, acc);
        pconv_chunk<4, 8>(hplane, wl, lane, acc);
    }
    float bv = (q == 0) ? bias[co] : 0.f;             // bias added exactly once
    float* outp = parts + (size_t)q * 2359296 + (size_t)n * 9216 + (size_t)co * 36;
    #pragma unroll
    for (int p = 0; p < 9; p++)
        ((float4*)outp)[p] = make_float4(acc[4*p] + bv, acc[4*p+1] + bv,
                                         acc[4*p+2] + bv, acc[4*p+3] + bv);
}

// ---------------- combine 4 ci-quarter partials + squash over 8-dim capsules ----------------
__global__ __launch_bounds__(256) void squash_u_kernel(
    const float* __restrict__ parts, float* __restrict__ u)
{
    int cap = blockIdx.x * 256 + threadIdx.x;   // 0..294911
    float z[8] = {0, 0, 0, 0, 0, 0, 0, 0};
    #pragma unroll
    for (int q = 0; q < 4; ++q) {
        const float4* a = (const float4*)(parts + (size_t)q * 2359296 + (size_t)cap * 8);
        float4 x0 = a[0], x1 = a[1];
        z[0] += x0.x; z[1] += x0.y; z[2] += x0.z; z[3] += x0.w;
        z[4] += x1.x; z[5] += x1.y; z[6] += x1.z; z[7] += x1.w;
    }
    float n2 = 0.f;
    #pragma unroll
    for (int k = 0; k < 8; k++) n2 += z[k] * z[k];
    float sc = sqrtf(n2) / (1.0f + n2);          // squash(x) = x*|x|/(1+|x|^2)
    float4* op = (float4*)(u + (size_t)cap * 8);
    op[0] = make_float4(z[0]*sc, z[1]*sc, z[2]*sc, z[3]*sc);
    op[1] = make_float4(z[4]*sc, z[5]*sc, z[6]*sc, z[7]*sc);
}

// ---------------- softmax over j=10 ----------------
__global__ void softmax_c_kernel(const float* __restrict__ b, float* __restrict__ c)
{
    int i = blockIdx.x * 256 + threadIdx.x;
    if (i >= 1152) return;
    float e[10], m = -1e30f;
    #pragma unroll
    for (int j = 0; j < 10; j++) { e[j] = b[i * 10 + j]; m = fmaxf(m, e[j]); }
    float sum = 0.f;
    #pragma unroll
    for (int j = 0; j < 10; j++) { e[j] = expf(e[j] - m); sum += e[j]; }
    float inv = 1.f / sum;
    #pragma unroll
    for (int j = 0; j < 10; j++) c[i * 10 + j] = e[j] * inv;
}

// ---------------- s[n,j,a] = sum_i c[i,j] * dot8(W[i,j,a,:], u[n,i,:]) ----------------
__global__ __launch_bounds__(256) void s_kernel(
    const float* __restrict__ c, const float* __restrict__ u,
    const float* __restrict__ W, float* __restrict__ s0, float* __restrict__ s1)
{
    int t = threadIdx.x;
    int a = t & 15, n_l = t >> 4;
    int j = blockIdx.x;
    int n = blockIdx.y * 16 + n_l;
    float* sout = (blockIdx.z == 0) ? s0 : s1;
    int i0 = blockIdx.z * 576;
    float acc = 0.f;
    for (int i = i0; i < i0 + 576; ++i) {
        float cij = c[i * 10 + j];                                  // block-uniform
        const float4* wp = (const float4*)&W[(((size_t)i * 10 + j) * 16 + a) * 8];
        float4 w0 = wp[0], w1 = wp[1];
        const float4* up = (const float4*)&u[(size_t)n * 9216 + (size_t)i * 8];
        float4 q0 = up[0], q1 = up[1];
        float d = w0.x*q0.x + w0.y*q0.y + w0.z*q0.z + w0.w*q0.w
                + w1.x*q1.x + w1.y*q1.y + w1.z*q1.z + w1.w*q1.w;
        acc += cij * d;
    }
    sout[((size_t)n * 10 + j) * 16 + a] = acc;
}

// ---------------- v = squash(s0+s1) over 16-dim; optionally emit to d_out ----------------
__global__ void squash_v_kernel(const float* __restrict__ s0, const float* __restrict__ s1,
                                float* __restrict__ v, float* __restrict__ vout)
{
    int idx = blockIdx.x * 256 + threadIdx.x;    // (n*10+j) in 0..2559
    if (idx >= 2560) return;
    float xv[16], n2 = 0.f;
    #pragma unroll
    for (int a = 0; a < 16; a++) {
        xv[a] = s0[idx * 16 + a] + s1[idx * 16 + a];
        n2 += xv[a] * xv[a];
    }
    float sc = sqrtf(n2) / (1.0f + n2);
    #pragma unroll
    for (int a = 0; a < 16; a++) {
        float y = xv[a] * sc;
        v[idx * 16 + a] = y;
        if (vout) vout[idx * 16 + a] = y;
    }
}

// ---------------- b[i,j] += sum_{a,b} W[i,j,a,b] * (sum_n u[n,i,b]*v[n,j,a]) ----------------
__global__ __launch_bounds__(192) void bupd_kernel(
    const float* __restrict__ u, const float* __restrict__ v,
    const float* __restrict__ W, float* __restrict__ b)
{
    int i = blockIdx.x;
    int t = threadIdx.x;
    if (t >= 160) return;
    int j = t >> 4, a = t & 15;
    float g[8];
    #pragma unroll
    for (int k = 0; k < 8; k++) g[k] = 0.f;
    for (int n = 0; n < 256; ++n) {
        float vv = v[n * 160 + t];                                  // coalesced
        const float4* up = (const float4*)&u[(size_t)n * 9216 + (size_t)i * 8];  // uniform
        float4 q0 = up[0], q1 = up[1];
        g[0] += q0.x * vv; g[1] += q0.y * vv; g[2] += q0.z * vv; g[3] += q0.w * vv;
        g[4] += q1.x * vv; g[5] += q1.y * vv; g[6] += q1.z * vv; g[7] += q1.w * vv;
    }
    const float4* wp = (const float4*)&W[(((size_t)i * 10 + j) * 16 + a) * 8];
    float4 w0 = wp[0], w1 = wp[1];
    float p = w0.x*g[0] + w0.y*g[1] + w0.z*g[2] + w0.w*g[3]
            + w1.x*g[4] + w1.y*g[5] + w1.z*g[6] + w1.w*g[7];
    p += __shfl_xor(p, 1);
    p += __shfl_xor(p, 2);
    p += __shfl_xor(p, 4);
    p += __shfl_xor(p, 8);
    if (a == 0) b[i * 10 + j] += p;
}

// ---------------- argmax(|v|) + mask -> decoder input (256,160) ----------------
__global__ void mask_kernel(const float* __restrict__ v, float* __restrict__ out)
{
    int n = threadIdx.x;                         // one block of 256
    const float* vp = &v[n * 160];
    int best = 0; float bestv = -1.f;
    for (int j = 0; j < 10; j++) {
        float n2 = 0.f;
        #pragma unroll
        for (int a = 0; a < 16; a++) { float y = vp[j * 16 + a]; n2 += y * y; }
        float ln = sqrtf(n2);
        if (ln > bestv) { bestv = ln; best = j; }  // strict > = first max (jnp.argmax)
    }
    for (int j = 0; j < 10; j++)
        for (int a = 0; a < 16; a++)
            out[n * 160 + j * 16 + a] = (j == best) ? vp[j * 16 + a] : 0.f;
}

// ---------------- decoder GEMM: out(256,O) = act(X(256,K) @ W(K,O) + bias) ----------------
__global__ __launch_bounds__(256) void mlp_kernel(
    const float* __restrict__ X, const float* __restrict__ Wm,
    const float* __restrict__ bias, float* __restrict__ out,
    int K, int O, int act)
{
    __shared__ float XS[64 * 36];                // [k][n] padded to 36
    int t = threadIdx.x;
    int og = t & 63, ns = t >> 6;
    int n0 = blockIdx.x * 32;
    int o = blockIdx.y * 256 + og * 4;
    int o_c = min(o, O - 4);
    float acc[8][4];
    #pragma unroll
    for (int s = 0; s < 8; s++)
        #pragma unroll
        for (int q = 0; q < 4; q++) acc[s][q] = 0.f;

    for (int kc = 0; kc < K; kc += 64) {
        int kn = min(64, K - kc);
        __syncthreads();
        for (int idx = t; idx < 2048; idx += 256) {
            int k_l = idx & 63, n_l = idx >> 6;
            XS[k_l * 36 + n_l] = (k_l < kn) ? X[(size_t)(n0 + n_l) * K + kc + k_l] : 0.f;
        }
        __syncthreads();
        for (int k = 0; k < kn; ++k) {
            float4 wv = *(const float4*)&Wm[(size_t)(kc + k) * O + o_c];
            float4 xa = *(const float4*)&XS[k * 36 + ns * 8];
            float4 xb = *(const float4*)&XS[k * 36 + ns * 8 + 4];
            float xs8[8] = {xa.x, xa.y, xa.z, xa.w, xb.x, xb.y, xb.z, xb.w};
            #pragma unroll
            for (int s = 0; s < 8; s++) {
                acc[s][0] += xs8[s] * wv.x;
                acc[s][1] += xs8[s] * wv.y;
                acc[s][2] += xs8[s] * wv.z;
                acc[s][3] += xs8[s] * wv.w;
            }
        }
    }
    if (o < O) {
        float4 bv = *(const float4*)&bias[o];
        #pragma unroll
        for (int s = 0; s < 8; s++) {
            float r[4] = {acc[s][0] + bv.x, acc[s][1] + bv.y, acc[s][2] + bv.z, acc[s][3] + bv.w};
            #pragma unroll
            for (int q = 0; q < 4; q++)
                r[q] = (act == 0) ? fmaxf(r[q], 0.f) : (1.f / (1.f + expf(-r[q])));
            *(float4*)&out[(size_t)(n0 + ns * 8 + s) * O + o] = make_float4(r[0], r[1], r[2], r[3]);
        }
    }
}

extern "C" void kernel_launch(void* const* d_in, const int* in_sizes, int n_in,
                              void* d_out, int out_size, void* d_ws, size_t ws_size,
                              hipStream_t stream)
{
    const float* x       = (const float*)d_in[0];
    const float* conv1_w = (const float*)d_in[1];
    const float* conv1_b = (const float*)d_in[2];
    const float* pconv_w = (const float*)d_in[3];
    const float* pconv_b = (const float*)d_in[4];
    const float* W_caps  = (const float*)d_in[5];
    const float* dec_w1  = (const float*)d_in[6];
    const float* dec_b1  = (const float*)d_in[7];
    const float* dec_w2  = (const float*)d_in[8];
    const float* dec_b2  = (const float*)d_in[9];
    const float* dec_w3  = (const float*)d_in[10];
    const float* dec_b3  = (const float*)d_in[11];
    float* out = (float*)d_out;

    float* ws = (float*)d_ws;
    size_t off = 0;
    auto alloc = [&](size_t nf) { float* p = ws + off; off += (nf + 63) & ~(size_t)63; return p; };
    float* conv1_out = alloc(26214400);   // (256,256,20,20)
    float* parts     = alloc(4 * 2359296);// pconv ci-quarter partials
    float* u_in      = alloc(2359296);    // squashed (256,1152,8)
    float* bbuf      = alloc(11520);      // routing logits b (1152,10)
    float* cbuf      = alloc(11520);
    float* s0        = alloc(40960);      // s partials (i-halves)
    float* s1        = alloc(40960);
    float* vbuf      = alloc(40960);      // v (256,10,16)
    float* rin       = alloc(40960);      // masked decoder input (256,160)
    float* h1        = alloc(131072);
    float* h2        = alloc(262144);

    hipMemsetAsync(bbuf, 0, 11520 * sizeof(float), stream);

    conv1_kernel<<<dim3(256, 4), 256, 0, stream>>>(x, conv1_w, conv1_b, conv1_out);
    pconv_kernel<<<dim3(64, 4, 4), 256, 0, stream>>>(conv1_out, pconv_w, pconv_b, parts);
    squash_u_kernel<<<1152, 256, 0, stream>>>(parts, u_in);

    for (int r = 0; r < 4; ++r) {
        softmax_c_kernel<<<5, 256, 0, stream>>>(bbuf, cbuf);
        s_kernel<<<dim3(10, 16, 2), 256, 0, stream>>>(cbuf, u_in, W_caps, s0, s1);
        squash_v_kernel<<<10, 256, 0, stream>>>(s0, s1, vbuf, (r == 3) ? out : nullptr);
        if (r < 3) bupd_kernel<<<1152, 192, 0, stream>>>(u_in, vbuf, W_caps, bbuf);
    }

    mask_kernel<<<1, 256, 0, stream>>>(vbuf, rin);
    mlp_kernel<<<dim3(8, 2), 256, 0, stream>>>(rin, dec_w1, dec_b1, h1, 160, 512, 0);
    mlp_kernel<<<dim3(8, 4), 256, 0, stream>>>(h1, dec_w2, dec_b2, h2, 512, 1024, 0);
    mlp_kernel<<<dim3(8, 4), 256, 0, stream>>>(h2, dec_w3, dec_b3, out + 40960, 1024, 784, 1);
}

// Round 3
// 3899.915 us; speedup vs baseline: 1.9250x; 1.1550x over previous
//
#include <hip/hip_runtime.h>
#include <math.h>

// CapsNet forward, fp32. Round 3: empirical launch_bounds rule (cap = 256/arg2):
// pconv goes LDS-free (repacked per-co weight streams, wave-uniform x rows),
// conv1 gets 128-VGPR cap to stop scratch spills.

// ---------------- one-time weight repack: w[co][ci][81] -> wr[co][ci][84] ----------------
__global__ __launch_bounds__(256) void repack_w_kernel(
    const float* __restrict__ w, float* __restrict__ wr)
{
    int idx = blockIdx.x * 256 + threadIdx.x;     // over 256*256*84
    if (idx >= 256 * 256 * 84) return;
    int k = idx % 84, rc = idx / 84;              // rc = co*256+ci
    wr[idx] = (k < 81) ? w[rc * 81 + k] : 0.f;
}

// ---------------- conv1: x(256,1,28,28) * w(256,81) -> out(256,256,20,20) ----------------
__global__ __launch_bounds__(256, 2) void conv1_kernel(
    const float* __restrict__ x, const float* __restrict__ w,
    const float* __restrict__ bias, float* __restrict__ out)
{
    __shared__ float xs[784];        // 28x28 input plane
    __shared__ float wl[64 * 81];    // [co_local][k]
    int t = threadIdx.x;
    int n = blockIdx.x;
    int cot = blockIdx.y;            // 4 tiles of 64 co

    for (int j = t; j < 784; j += 256) xs[j] = x[n * 784 + j];
    {   // div/mod-free staging: 4 threads per co row, 21-float segments
        int co_s = t >> 2, k0 = (t & 3) * 21;
        const float* wsrc = w + (size_t)(cot * 64 + co_s) * 81;
        #pragma unroll
        for (int k = 0; k < 21; ++k)
            if (k0 + k < 81) wl[co_s * 81 + k0 + k] = wsrc[k0 + k];
    }
    __syncthreads();

    int co_l = t & 63, slot = t >> 6;   // wave = one row-slot, 64 co per wave
    int co = cot * 64 + co_l;
    float bv = bias[co];
    for (int r5 = 0; r5 < 5; ++r5) {
        int py = slot * 5 + r5;          // output row 0..19
        float acc[20];
        #pragma unroll
        for (int i = 0; i < 20; i++) acc[i] = bv;
        #pragma unroll
        for (int ky = 0; ky < 9; ++ky) {
            float xr[28];
            const float4* rowp = (const float4*)&xs[(py + ky) * 28];
            #pragma unroll
            for (int q = 0; q < 7; q++) {
                float4 v4 = rowp[q];
                xr[4*q] = v4.x; xr[4*q+1] = v4.y; xr[4*q+2] = v4.z; xr[4*q+3] = v4.w;
            }
            #pragma unroll
            for (int kx = 0; kx < 9; ++kx) {
                float wv = wl[co_l * 81 + ky * 9 + kx];
                #pragma unroll
                for (int px = 0; px < 20; ++px) acc[px] += wv * xr[px + kx];
            }
        }
        float* op = &out[(size_t)n * 102400 + (size_t)co * 400 + py * 20];
        #pragma unroll
        for (int q = 0; q < 5; q++)
            ((float4*)op)[q] = make_float4(acc[4*q], acc[4*q+1], acc[4*q+2], acc[4*q+3]);
    }
}

// ---------------- pconv: h(256,256,20,20) * wr(256,256,84) stride2 -> partials ----------------
// Wave = one n-plane, 64 lanes = 64 co. Weights stream per-lane from global
// (contiguous 336B/ci per lane, dwordx4); x rows are wave-uniform global
// float4 loads (scalar-promotable -> SGPR operands). No LDS, no barriers.
template<int KY0, int KY1>
__device__ __forceinline__ void pconv_chunk_g(const float* __restrict__ hplane,
                                              const float* __restrict__ wp,
                                              float* __restrict__ acc)
{
    constexpr int NK = (KY1 - KY0 + 1) * 9;           // 36 or 45
    constexpr int NQ = (NK + 3) / 4;                  // 9 or 12
    float wreg[NQ * 4];
    #pragma unroll
    for (int qq = 0; qq < NQ; ++qq) {
        float4 v4 = *(const float4*)(wp + KY0 * 9 + qq * 4);   // 16B-aligned (pad 84)
        wreg[qq*4+0] = v4.x; wreg[qq*4+1] = v4.y; wreg[qq*4+2] = v4.z; wreg[qq*4+3] = v4.w;
    }
    constexpr int RMAX = (10 + KY1 < 18) ? (10 + KY1) : 18;    // last used input row = 18
    #pragma unroll
    for (int r = KY0; r <= RMAX; ++r) {
        float xr[20];
        #pragma unroll
        for (int q2 = 0; q2 < 5; ++q2) {
            float4 v4 = *(const float4*)(hplane + r * 20 + q2 * 4);  // uniform addr
            xr[4*q2+0] = v4.x; xr[4*q2+1] = v4.y; xr[4*q2+2] = v4.z; xr[4*q2+3] = v4.w;
        }
        #pragma unroll
        for (int oy = 0; oy < 6; ++oy) {
            int ky = r - 2 * oy;                       // constant after unroll
            if (ky >= KY0 && ky <= KY1) {
                #pragma unroll
                for (int kx = 0; kx < 9; ++kx) {
                    float wv = wreg[(ky - KY0) * 9 + kx];
                    #pragma unroll
                    for (int ox = 0; ox < 6; ++ox)
                        acc[oy * 6 + ox] += wv * xr[2 * ox + kx];
                }
            }
        }
    }
}

__global__ __launch_bounds__(256, 2) void pconv_kernel(
    const float* __restrict__ h, const float* __restrict__ wr,
    const float* __restrict__ bias, float* __restrict__ parts)
{
    int t = threadIdx.x;
    int lane = t & 63;
    int wid = __builtin_amdgcn_readfirstlane(t >> 6);  // force wave-uniform
    int ng = blockIdx.x;              // 64 groups of 4 batches
    int cot = blockIdx.y;             // 4 tiles of 64 co
    int q = blockIdx.z;               // ci quarter
    int n = ng * 4 + wid;
    int co = cot * 64 + lane;

    float acc[36];
    #pragma unroll
    for (int i = 0; i < 36; i++) acc[i] = 0.f;

    const float* hn = h + (size_t)n * 102400 + (size_t)q * 64 * 400;
    const float* wb = wr + (size_t)co * (256 * 84) + (size_t)q * 64 * 84;
    for (int ci = 0; ci < 64; ++ci) {
        const float* hplane = hn + (size_t)ci * 400;
        const float* wp = wb + ci * 84;
        pconv_chunk_g<0, 3>(hplane, wp, acc);
        pconv_chunk_g<4, 8>(hplane, wp, acc);
    }
    float bv = (q == 0) ? bias[co] : 0.f;             // bias added exactly once
    float* outp = parts + (size_t)q * 2359296 + (size_t)n * 9216 + (size_t)co * 36;
    #pragma unroll
    for (int p = 0; p < 9; p++)
        ((float4*)outp)[p] = make_float4(acc[4*p] + bv, acc[4*p+1] + bv,
                                         acc[4*p+2] + bv, acc[4*p+3] + bv);
}

// ---------------- combine 4 ci-quarter partials + squash over 8-dim capsules ----------------
__global__ __launch_bounds__(256) void squash_u_kernel(
    const float* __restrict__ parts, float* __restrict__ u)
{
    int cap = blockIdx.x * 256 + threadIdx.x;   // 0..294911
    float z[8] = {0, 0, 0, 0, 0, 0, 0, 0};
    #pragma unroll
    for (int q = 0; q < 4; ++q) {
        const float4* a = (const float4*)(parts + (size_t)q * 2359296 + (size_t)cap * 8);
        float4 x0 = a[0], x1 = a[1];
        z[0] += x0.x; z[1] += x0.y; z[2] += x0.z; z[3] += x0.w;
        z[4] += x1.x; z[5] += x1.y; z[6] += x1.z; z[7] += x1.w;
    }
    float n2 = 0.f;
    #pragma unroll
    for (int k = 0; k < 8; k++) n2 += z[k] * z[k];
    float sc = sqrtf(n2) / (1.0f + n2);          // squash(x) = x*|x|/(1+|x|^2)
    float4* op = (float4*)(u + (size_t)cap * 8);
    op[0] = make_float4(z[0]*sc, z[1]*sc, z[2]*sc, z[3]*sc);
    op[1] = make_float4(z[4]*sc, z[5]*sc, z[6]*sc, z[7]*sc);
}

// ---------------- softmax over j=10 ----------------
__global__ void softmax_c_kernel(const float* __restrict__ b, float* __restrict__ c)
{
    int i = blockIdx.x * 256 + threadIdx.x;
    if (i >= 1152) return;
    float e[10], m = -1e30f;
    #pragma unroll
    for (int j = 0; j < 10; j++) { e[j] = b[i * 10 + j]; m = fmaxf(m, e[j]); }
    float sum = 0.f;
    #pragma unroll
    for (int j = 0; j < 10; j++) { e[j] = expf(e[j] - m); sum += e[j]; }
    float inv = 1.f / sum;
    #pragma unroll
    for (int j = 0; j < 10; j++) c[i * 10 + j] = e[j] * inv;
}

// ---------------- s[n,j,a] partials over 4 i-chunks ----------------
__global__ __launch_bounds__(256) void s_kernel(
    const float* __restrict__ c, const float* __restrict__ u,
    const float* __restrict__ W, float* __restrict__ sbuf)
{
    int t = threadIdx.x;
    int a = t & 15, n_l = t >> 4;
    int j = blockIdx.x;
    int n = blockIdx.y * 16 + n_l;
    int i0 = blockIdx.z * 288;
    float acc = 0.f;
    for (int i = i0; i < i0 + 288; ++i) {
        float cij = c[i * 10 + j];                                  // block-uniform
        const float4* wp = (const float4*)&W[(((size_t)i * 10 + j) * 16 + a) * 8];
        float4 w0 = wp[0], w1 = wp[1];
        const float4* up = (const float4*)&u[(size_t)n * 9216 + (size_t)i * 8];
        float4 q0 = up[0], q1 = up[1];
        float d = w0.x*q0.x + w0.y*q0.y + w0.z*q0.z + w0.w*q0.w
                + w1.x*q1.x + w1.y*q1.y + w1.z*q1.z + w1.w*q1.w;
        acc += cij * d;
    }
    sbuf[(size_t)blockIdx.z * 40960 + ((size_t)n * 10 + j) * 16 + a] = acc;
}

// ---------------- v = squash(sum of 4 s-partials) over 16-dim ----------------
__global__ void squash_v_kernel(const float* __restrict__ sbuf,
                                float* __restrict__ v, float* __restrict__ vout)
{
    int idx = blockIdx.x * 256 + threadIdx.x;    // (n*10+j) in 0..2559
    if (idx >= 2560) return;
    float xv[16], n2 = 0.f;
    #pragma unroll
    for (int a = 0; a < 16; a++) {
        float s = sbuf[idx * 16 + a] + sbuf[40960 + idx * 16 + a]
                + sbuf[81920 + idx * 16 + a] + sbuf[122880 + idx * 16 + a];
        xv[a] = s;
        n2 += s * s;
    }
    float sc = sqrtf(n2) / (1.0f + n2);
    #pragma unroll
    for (int a = 0; a < 16; a++) {
        float y = xv[a] * sc;
        v[idx * 16 + a] = y;
        if (vout) vout[idx * 16 + a] = y;
    }
}

// ---------------- b[i,j] += sum_{a,b} W[i,j,a,b] * (sum_n u[n,i,b]*v[n,j,a]) ----------------
__global__ __launch_bounds__(192) void bupd_kernel(
    const float* __restrict__ u, const float* __restrict__ v,
    const float* __restrict__ W, float* __restrict__ b)
{
    int i = blockIdx.x;
    int t = threadIdx.x;
    if (t >= 160) return;
    int j = t >> 4, a = t & 15;
    float g[8];
    #pragma unroll
    for (int k = 0; k < 8; k++) g[k] = 0.f;
    for (int n = 0; n < 256; ++n) {
        float vv = v[n * 160 + t];                                  // coalesced
        const float4* up = (const float4*)&u[(size_t)n * 9216 + (size_t)i * 8];  // uniform
        float4 q0 = up[0], q1 = up[1];
        g[0] += q0.x * vv; g[1] += q0.y * vv; g[2] += q0.z * vv; g[3] += q0.w * vv;
        g[4] += q1.x * vv; g[5] += q1.y * vv; g[6] += q1.z * vv; g[7] += q1.w * vv;
    }
    const float4* wp = (const float4*)&W[(((size_t)i * 10 + j) * 16 + a) * 8];
    float4 w0 = wp[0], w1 = wp[1];
    float p = w0.x*g[0] + w0.y*g[1] + w0.z*g[2] + w0.w*g[3]
            + w1.x*g[4] + w1.y*g[5] + w1.z*g[6] + w1.w*g[7];
    p += __shfl_xor(p, 1);
    p += __shfl_xor(p, 2);
    p += __shfl_xor(p, 4);
    p += __shfl_xor(p, 8);
    if (a == 0) b[i * 10 + j] += p;
}

// ---------------- argmax(|v|) + mask -> decoder input (256,160) ----------------
__global__ void mask_kernel(const float* __restrict__ v, float* __restrict__ out)
{
    int n = threadIdx.x;                         // one block of 256
    const float* vp = &v[n * 160];
    int best = 0; float bestv = -1.f;
    for (int j = 0; j < 10; j++) {
        float n2 = 0.f;
        #pragma unroll
        for (int a = 0; a < 16; a++) { float y = vp[j * 16 + a]; n2 += y * y; }
        float ln = sqrtf(n2);
        if (ln > bestv) { bestv = ln; best = j; }  // strict > = first max (jnp.argmax)
    }
    for (int j = 0; j < 10; j++)
        for (int a = 0; a < 16; a++)
            out[n * 160 + j * 16 + a] = (j == best) ? vp[j * 16 + a] : 0.f;
}

// ---------------- decoder GEMM: out(256,O) = act(X(256,K) @ W(K,O) + bias) ----------------
__global__ __launch_bounds__(256, 1) void mlp_kernel(
    const float* __restrict__ X, const float* __restrict__ Wm,
    const float* __restrict__ bias, float* __restrict__ out,
    int K, int O, int act)
{
    __shared__ float XS[64 * 36];                // [k][n] padded to 36
    int t = threadIdx.x;
    int og = t & 63, ns = t >> 6;
    int n0 = blockIdx.x * 32;
    int o = blockIdx.y * 256 + og * 4;
    int o_c = min(o, O - 4);
    float acc[8][4];
    #pragma unroll
    for (int s = 0; s < 8; s++)
        #pragma unroll
        for (int q = 0; q < 4; q++) acc[s][q] = 0.f;

    for (int kc = 0; kc < K; kc += 64) {
        int kn = min(64, K - kc);
        __syncthreads();
        for (int idx = t; idx < 2048; idx += 256) {
            int k_l = idx & 63, n_l = idx >> 6;
            XS[k_l * 36 + n_l] = (k_l < kn) ? X[(size_t)(n0 + n_l) * K + kc + k_l] : 0.f;
        }
        __syncthreads();
        for (int k = 0; k < kn; ++k) {
            float4 wv = *(const float4*)&Wm[(size_t)(kc + k) * O + o_c];
            float4 xa = *(const float4*)&XS[k * 36 + ns * 8];
            float4 xb = *(const float4*)&XS[k * 36 + ns * 8 + 4];
            float xs8[8] = {xa.x, xa.y, xa.z, xa.w, xb.x, xb.y, xb.z, xb.w};
            #pragma unroll
            for (int s = 0; s < 8; s++) {
                acc[s][0] += xs8[s] * wv.x;
                acc[s][1] += xs8[s] * wv.y;
                acc[s][2] += xs8[s] * wv.z;
                acc[s][3] += xs8[s] * wv.w;
            }
        }
    }
    if (o < O) {
        float4 bv = *(const float4*)&bias[o];
        #pragma unroll
        for (int s = 0; s < 8; s++) {
            float r[4] = {acc[s][0] + bv.x, acc[s][1] + bv.y, acc[s][2] + bv.z, acc[s][3] + bv.w};
            #pragma unroll
            for (int q = 0; q < 4; q++)
                r[q] = (act == 0) ? fmaxf(r[q], 0.f) : (1.f / (1.f + expf(-r[q])));
            *(float4*)&out[(size_t)(n0 + ns * 8 + s) * O + o] = make_float4(r[0], r[1], r[2], r[3]);
        }
    }
}

extern "C" void kernel_launch(void* const* d_in, const int* in_sizes, int n_in,
                              void* d_out, int out_size, void* d_ws, size_t ws_size,
                              hipStream_t stream)
{
    const float* x       = (const float*)d_in[0];
    const float* conv1_w = (const float*)d_in[1];
    const float* conv1_b = (const float*)d_in[2];
    const float* pconv_w = (const float*)d_in[3];
    const float* pconv_b = (const float*)d_in[4];
    const float* W_caps  = (const float*)d_in[5];
    const float* dec_w1  = (const float*)d_in[6];
    const float* dec_b1  = (const float*)d_in[7];
    const float* dec_w2  = (const float*)d_in[8];
    const float* dec_b2  = (const float*)d_in[9];
    const float* dec_w3  = (const float*)d_in[10];
    const float* dec_b3  = (const float*)d_in[11];
    float* out = (float*)d_out;

    float* ws = (float*)d_ws;
    size_t off = 0;
    auto alloc = [&](size_t nf) { float* p = ws + off; off += (nf + 63) & ~(size_t)63; return p; };
    float* conv1_out = alloc(26214400);    // (256,256,20,20)
    float* parts     = alloc(4 * 2359296); // pconv ci-quarter partials
    float* wr        = alloc(256*256*84);  // repacked pconv weights
    float* u_in      = alloc(2359296);     // squashed (256,1152,8)
    float* bbuf      = alloc(11520);       // routing logits b (1152,10)
    float* cbuf      = alloc(11520);
    float* sbuf      = alloc(4 * 40960);   // s partials (4 i-chunks)
    float* vbuf      = alloc(40960);       // v (256,10,16)
    float* rin       = alloc(40960);       // masked decoder input (256,160)
    float* h1        = alloc(131072);
    float* h2        = alloc(262144);

    hipMemsetAsync(bbuf, 0, 11520 * sizeof(float), stream);

    repack_w_kernel<<<(256*256*84 + 255) / 256, 256, 0, stream>>>(pconv_w, wr);
    conv1_kernel<<<dim3(256, 4), 256, 0, stream>>>(x, conv1_w, conv1_b, conv1_out);
    pconv_kernel<<<dim3(64, 4, 4), 256, 0, stream>>>(conv1_out, wr, pconv_b, parts);
    squash_u_kernel<<<1152, 256, 0, stream>>>(parts, u_in);

    for (int r = 0; r < 4; ++r) {
        softmax_c_kernel<<<5, 256, 0, stream>>>(bbuf, cbuf);
        s_kernel<<<dim3(10, 16, 4), 256, 0, stream>>>(cbuf, u_in, W_caps, sbuf);
        squash_v_kernel<<<10, 256, 0, stream>>>(sbuf, vbuf, (r == 3) ? out : nullptr);
        if (r < 3) bupd_kernel<<<1152, 192, 0, stream>>>(u_in, vbuf, W_caps, bbuf);
    }

    mask_kernel<<<1, 256, 0, stream>>>(vbuf, rin);
    mlp_kernel<<<dim3(8, 2), 256, 0, stream>>>(rin, dec_w1, dec_b1, h1, 160, 512, 0);
    mlp_kernel<<<dim3(8, 4), 256, 0, stream>>>(h1, dec_w2, dec_b2, h2, 512, 1024, 0);
    mlp_kernel<<<dim3(8, 4), 256, 0, stream>>>(h2, dec_w3, dec_b3, out + 40960, 1024, 784, 1);
}

// Round 4
// 2149.340 us; speedup vs baseline: 3.4929x; 1.8145x over previous
//
#include <hip/hip_runtime.h>
#include <math.h>

// CapsNet forward. Round 4: pconv via MFMA bf16 3-term split (implicit GEMM,
// M=9216 (n,oy,ox) x N=256 co x K=20736 (ci,ky,kx)); conv1 emits packed
// bf16 hi/lo NHWC directly; weights repacked to MFMA-frag-linear layout.

typedef __attribute__((ext_vector_type(8))) short short8;
typedef __attribute__((ext_vector_type(4))) float floatx4;

__device__ __forceinline__ unsigned short bf16_rne(float f) {
    unsigned int u = __float_as_uint(f);
    return (unsigned short)((u + 0x7FFFu + ((u >> 16) & 1u)) >> 16);
}
__device__ __forceinline__ float bf16_tof(unsigned short h) {
    return __uint_as_float((unsigned int)h << 16);
}

// ---------------- conv1: x(256,1,28,28) * w(256,81) -> xpack NHWC bf16 hi/lo ----------------
// xpack layout (ushort): [pix = n*400 + y*20 + x][2][256]  (hi plane, lo plane)
__global__ __launch_bounds__(256, 2) void conv1_kernel(
    const float* __restrict__ x, const float* __restrict__ w,
    const float* __restrict__ bias, unsigned short* __restrict__ xpack)
{
    __shared__ float xs[784];        // 28x28 input plane
    __shared__ float wl[64 * 81];    // [co_local][k]
    int t = threadIdx.x;
    int n = blockIdx.x;
    int cot = blockIdx.y;            // 4 tiles of 64 co

    for (int j = t; j < 784; j += 256) xs[j] = x[n * 784 + j];
    {   // 4 threads per co row, 21-float segments
        int co_s = t >> 2, k0 = (t & 3) * 21;
        const float* wsrc = w + (size_t)(cot * 64 + co_s) * 81;
        #pragma unroll
        for (int k = 0; k < 21; ++k)
            if (k0 + k < 81) wl[co_s * 81 + k0 + k] = wsrc[k0 + k];
    }
    __syncthreads();

    int co_l = t & 63, slot = t >> 6;   // wave = one row-slot, 64 co per wave
    int co = cot * 64 + co_l;
    float bv = bias[co];
    for (int r5 = 0; r5 < 5; ++r5) {
        int py = slot * 5 + r5;          // output row 0..19
        float acc[20];
        #pragma unroll
        for (int i = 0; i < 20; i++) acc[i] = bv;
        #pragma unroll
        for (int ky = 0; ky < 9; ++ky) {
            float xr[28];
            const float4* rowp = (const float4*)&xs[(py + ky) * 28];
            #pragma unroll
            for (int q = 0; q < 7; q++) {
                float4 v4 = rowp[q];
                xr[4*q] = v4.x; xr[4*q+1] = v4.y; xr[4*q+2] = v4.z; xr[4*q+3] = v4.w;
            }
            #pragma unroll
            for (int kx = 0; kx < 9; ++kx) {
                float wv = wl[co_l * 81 + ky * 9 + kx];
                #pragma unroll
                for (int px = 0; px < 20; ++px) acc[px] += wv * xr[px + kx];
            }
        }
        #pragma unroll
        for (int px = 0; px < 20; ++px) {
            float v = acc[px];
            unsigned short h = bf16_rne(v);
            unsigned short l = bf16_rne(v - bf16_tof(h));
            size_t pix = (size_t)n * 400 + py * 20 + px;
            xpack[pix * 512 + co] = h;
            xpack[pix * 512 + 256 + co] = l;
        }
    }
}

// ---------------- weight repack: w[co][ci][9][9] -> frag-linear bf16 hi/lo ----------------
// wpack (ushort): [gs = kk*8+cb][g = co>>4][2][64 lanes][8]  (hi block 512, lo block 512)
__global__ __launch_bounds__(256) void wpack_kernel(
    const float* __restrict__ w, unsigned short* __restrict__ wp)
{
    int tid = blockIdx.x * 256 + threadIdx.x;      // 648*16*64 = 663552
    if (tid >= 648 * 16 * 64) return;
    int lane = tid & 63, g = (tid >> 6) & 15, gs = tid >> 10;
    int cb = gs & 7, kk = gs >> 3;
    int ky = kk / 9, kx = kk - ky * 9;
    int n16 = lane & 15, q = lane >> 4;
    int co = g * 16 + n16;
    unsigned short hi[8], lo[8];
    #pragma unroll
    for (int j = 0; j < 8; ++j) {
        int ci = cb * 32 + q * 8 + j;
        float v = w[((size_t)co * 256 + ci) * 81 + ky * 9 + kx];
        hi[j] = bf16_rne(v);
        lo[j] = bf16_rne(v - bf16_tof(hi[j]));
    }
    unsigned short* dst = wp + ((size_t)gs * 16 + g) * 1024 + lane * 8;
    *(short8*)dst        = *(short8*)hi;
    *(short8*)(dst + 512) = *(short8*)lo;
}

// ---------------- pconv MFMA GEMM: P[n][co*36+pos] += A x B (3-term bf16) ----------------
// grid (mtile 72, cotile 2, kchunk 6), block 256 = 4 waves.
// wave(wid): mhalf=wid&1, chalf=wid>>1 -> 4 msub x 4 cosub 16x16 frags.
__global__ void pconv_mfma_kernel(
    const unsigned short* __restrict__ xp, const unsigned short* __restrict__ wp,
    float* __restrict__ P)
{
    int t = threadIdx.x;
    int lane = t & 63;
    int wid = __builtin_amdgcn_readfirstlane(t >> 6);
    int mhalf = wid & 1, chalf = wid >> 1;
    int r16 = lane & 15, q = lane >> 4;
    int mtile = blockIdx.x, cotile = blockIdx.y, kc = blockIdx.z;

    // per-lane A byte-offset bases for the 4 m-subtiles (A-frag row = lane&15)
    unsigned int abase[4];
    #pragma unroll
    for (int ms = 0; ms < 4; ++ms) {
        int m = mtile * 128 + mhalf * 64 + ms * 16 + r16;
        int n = m / 36, pos = m - n * 36;
        int oy = pos / 6, ox = pos - oy * 6;
        abase[ms] = (unsigned int)(((n * 400 + oy * 40 + ox * 2) * 1024) + q * 16);
    }

    floatx4 acc[4][4];
    #pragma unroll
    for (int a = 0; a < 4; ++a)
        #pragma unroll
        for (int b = 0; b < 4; ++b)
            acc[a][b] = (floatx4){0.f, 0.f, 0.f, 0.f};

    const char* xbytes = (const char*)xp;
    for (int s = 0; s < 108; ++s) {
        int gs = kc * 108 + s;                       // 0..647
        int cb = gs & 7, kk = gs >> 3;
        int ky = kk / 9, kx = kk - ky * 9;           // uniform scalars
        unsigned int aoff = (unsigned int)((ky * 20 + kx) * 1024 + cb * 64);

        short8 Ah[4], Al[4], Bh[4], Bl[4];
        #pragma unroll
        for (int ms = 0; ms < 4; ++ms) {
            const char* p = xbytes + abase[ms] + aoff;
            Ah[ms] = *(const short8*)p;
            Al[ms] = *(const short8*)(p + 512);
        }
        #pragma unroll
        for (int cs = 0; cs < 4; ++cs) {
            int g = cotile * 8 + chalf * 4 + cs;
            const unsigned short* bp = wp + ((size_t)gs * 16 + g) * 1024 + lane * 8;
            Bh[cs] = *(const short8*)bp;
            Bl[cs] = *(const short8*)(bp + 512);
        }
        #pragma unroll
        for (int ms = 0; ms < 4; ++ms)
            #pragma unroll
            for (int cs = 0; cs < 4; ++cs) {
                acc[ms][cs] = __builtin_amdgcn_mfma_f32_16x16x32_bf16(Ah[ms], Bh[cs], acc[ms][cs], 0, 0, 0);
                acc[ms][cs] = __builtin_amdgcn_mfma_f32_16x16x32_bf16(Ah[ms], Bl[cs], acc[ms][cs], 0, 0, 0);
                acc[ms][cs] = __builtin_amdgcn_mfma_f32_16x16x32_bf16(Al[ms], Bh[cs], acc[ms][cs], 0, 0, 0);
            }
    }

    // epilogue: C/D frag row = (lane>>4)*4 + reg, col = lane&15
    #pragma unroll
    for (int ms = 0; ms < 4; ++ms)
        #pragma unroll
        for (int r = 0; r < 4; ++r) {
            int m = mtile * 128 + mhalf * 64 + ms * 16 + q * 4 + r;
            int n = m / 36, pos = m - n * 36;
            #pragma unroll
            for (int cs = 0; cs < 4; ++cs) {
                int co = cotile * 128 + chalf * 64 + cs * 16 + r16;
                atomicAdd(&P[(size_t)n * 9216 + co * 36 + pos], acc[ms][cs][r]);
            }
        }
}

// ---------------- squash over 8-dim capsules (+pconv bias): u[i]=squash(P[i]+b) ----------------
__global__ __launch_bounds__(256) void squash_u_kernel(
    const float* __restrict__ P, const float* __restrict__ pb, float* __restrict__ u)
{
    int cap = blockIdx.x * 256 + threadIdx.x;   // 0..294911 ; P/u share flat layout
    int capl = cap & 1023;                       // cap % 1152 needs real mod:
    capl = cap - (cap / 1152) * 1152;
    int base = capl * 8;
    const float4* a = (const float4*)(P + (size_t)cap * 8);
    float4 x0 = a[0], x1 = a[1];
    float z[8] = {x0.x, x0.y, x0.z, x0.w, x1.x, x1.y, x1.z, x1.w};
    float n2 = 0.f;
    #pragma unroll
    for (int b = 0; b < 8; ++b) {
        z[b] += pb[(base + b) / 36];
        n2 += z[b] * z[b];
    }
    float sc = sqrtf(n2) / (1.0f + n2);          // squash = x*|x|/(1+|x|^2)
    float4* op = (float4*)(u + (size_t)cap * 8);
    op[0] = make_float4(z[0]*sc, z[1]*sc, z[2]*sc, z[3]*sc);
    op[1] = make_float4(z[4]*sc, z[5]*sc, z[6]*sc, z[7]*sc);
}

// ---------------- softmax over j=10 ----------------
__global__ void softmax_c_kernel(const float* __restrict__ b, float* __restrict__ c)
{
    int i = blockIdx.x * 256 + threadIdx.x;
    if (i >= 1152) return;
    float e[10], m = -1e30f;
    #pragma unroll
    for (int j = 0; j < 10; j++) { e[j] = b[i * 10 + j]; m = fmaxf(m, e[j]); }
    float sum = 0.f;
    #pragma unroll
    for (int j = 0; j < 10; j++) { e[j] = expf(e[j] - m); sum += e[j]; }
    float inv = 1.f / sum;
    #pragma unroll
    for (int j = 0; j < 10; j++) c[i * 10 + j] = e[j] * inv;
}

// ---------------- s[n,j,a] partials over 4 i-chunks ----------------
__global__ __launch_bounds__(256) void s_kernel(
    const float* __restrict__ c, const float* __restrict__ u,
    const float* __restrict__ W, float* __restrict__ sbuf)
{
    int t = threadIdx.x;
    int a = t & 15, n_l = t >> 4;
    int j = blockIdx.x;
    int n = blockIdx.y * 16 + n_l;
    int i0 = blockIdx.z * 288;
    float acc = 0.f;
    for (int i = i0; i < i0 + 288; ++i) {
        float cij = c[i * 10 + j];                                  // block-uniform
        const float4* wpt = (const float4*)&W[(((size_t)i * 10 + j) * 16 + a) * 8];
        float4 w0 = wpt[0], w1 = wpt[1];
        const float4* up = (const float4*)&u[(size_t)n * 9216 + (size_t)i * 8];
        float4 q0 = up[0], q1 = up[1];
        float d = w0.x*q0.x + w0.y*q0.y + w0.z*q0.z + w0.w*q0.w
                + w1.x*q1.x + w1.y*q1.y + w1.z*q1.z + w1.w*q1.w;
        acc += cij * d;
    }
    sbuf[(size_t)blockIdx.z * 40960 + ((size_t)n * 10 + j) * 16 + a] = acc;
}

// ---------------- v = squash(sum of 4 s-partials) over 16-dim ----------------
__global__ void squash_v_kernel(const float* __restrict__ sbuf,
                                float* __restrict__ v, float* __restrict__ vout)
{
    int idx = blockIdx.x * 256 + threadIdx.x;    // (n*10+j) in 0..2559
    if (idx >= 2560) return;
    float xv[16], n2 = 0.f;
    #pragma unroll
    for (int a = 0; a < 16; a++) {
        float s = sbuf[idx * 16 + a] + sbuf[40960 + idx * 16 + a]
                + sbuf[81920 + idx * 16 + a] + sbuf[122880 + idx * 16 + a];
        xv[a] = s;
        n2 += s * s;
    }
    float sc = sqrtf(n2) / (1.0f + n2);
    #pragma unroll
    for (int a = 0; a < 16; a++) {
        float y = xv[a] * sc;
        v[idx * 16 + a] = y;
        if (vout) vout[idx * 16 + a] = y;
    }
}

// ---------------- b[i,j] += sum_{a,b} W[i,j,a,b] * (sum_n u[n,i,b]*v[n,j,a]) ----------------
__global__ __launch_bounds__(192) void bupd_kernel(
    const float* __restrict__ u, const float* __restrict__ v,
    const float* __restrict__ W, float* __restrict__ b)
{
    int i = blockIdx.x;
    int t = threadIdx.x;
    if (t >= 160) return;
    int j = t >> 4, a = t & 15;
    float g[8];
    #pragma unroll
    for (int k = 0; k < 8; k++) g[k] = 0.f;
    for (int n = 0; n < 256; ++n) {
        float vv = v[n * 160 + t];                                  // coalesced
        const float4* up = (const float4*)&u[(size_t)n * 9216 + (size_t)i * 8];  // uniform
        float4 q0 = up[0], q1 = up[1];
        g[0] += q0.x * vv; g[1] += q0.y * vv; g[2] += q0.z * vv; g[3] += q0.w * vv;
        g[4] += q1.x * vv; g[5] += q1.y * vv; g[6] += q1.z * vv; g[7] += q1.w * vv;
    }
    const float4* wpt = (const float4*)&W[(((size_t)i * 10 + j) * 16 + a) * 8];
    float4 w0 = wpt[0], w1 = wpt[1];
    float p = w0.x*g[0] + w0.y*g[1] + w0.z*g[2] + w0.w*g[3]
            + w1.x*g[4] + w1.y*g[5] + w1.z*g[6] + w1.w*g[7];
    p += __shfl_xor(p, 1);
    p += __shfl_xor(p, 2);
    p += __shfl_xor(p, 4);
    p += __shfl_xor(p, 8);
    if (a == 0) b[i * 10 + j] += p;
}

// ---------------- argmax(|v|) + mask -> decoder input (256,160) ----------------
__global__ void mask_kernel(const float* __restrict__ v, float* __restrict__ out)
{
    int n = threadIdx.x;                         // one block of 256
    const float* vp = &v[n * 160];
    int best = 0; float bestv = -1.f;
    for (int j = 0; j < 10; j++) {
        float n2 = 0.f;
        #pragma unroll
        for (int a = 0; a < 16; a++) { float y = vp[j * 16 + a]; n2 += y * y; }
        float ln = sqrtf(n2);
        if (ln > bestv) { bestv = ln; best = j; }  // strict > = first max (jnp.argmax)
    }
    for (int j = 0; j < 10; j++)
        for (int a = 0; a < 16; a++)
            out[n * 160 + j * 16 + a] = (j == best) ? vp[j * 16 + a] : 0.f;
}

// ---------------- decoder GEMM: out(256,O) = act(X(256,K) @ W(K,O) + bias) ----------------
__global__ __launch_bounds__(256, 1) void mlp_kernel(
    const float* __restrict__ X, const float* __restrict__ Wm,
    const float* __restrict__ bias, float* __restrict__ out,
    int K, int O, int act)
{
    __shared__ float XS[64 * 36];                // [k][n] padded to 36
    int t = threadIdx.x;
    int og = t & 63, ns = t >> 6;
    int n0 = blockIdx.x * 32;
    int o = blockIdx.y * 256 + og * 4;
    int o_c = min(o, O - 4);
    float acc[8][4];
    #pragma unroll
    for (int s = 0; s < 8; s++)
        #pragma unroll
        for (int q = 0; q < 4; q++) acc[s][q] = 0.f;

    for (int kc = 0; kc < K; kc += 64) {
        int kn = min(64, K - kc);
        __syncthreads();
        for (int idx = t; idx < 2048; idx += 256) {
            int k_l = idx & 63, n_l = idx >> 6;
            XS[k_l * 36 + n_l] = (k_l < kn) ? X[(size_t)(n0 + n_l) * K + kc + k_l] : 0.f;
        }
        __syncthreads();
        for (int k = 0; k < kn; ++k) {
            float4 wv = *(const float4*)&Wm[(size_t)(kc + k) * O + o_c];
            float4 xa = *(const float4*)&XS[k * 36 + ns * 8];
            float4 xb = *(const float4*)&XS[k * 36 + ns * 8 + 4];
            float xs8[8] = {xa.x, xa.y, xa.z, xa.w, xb.x, xb.y, xb.z, xb.w};
            #pragma unroll
            for (int s = 0; s < 8; s++) {
                acc[s][0] += xs8[s] * wv.x;
                acc[s][1] += xs8[s] * wv.y;
                acc[s][2] += xs8[s] * wv.z;
                acc[s][3] += xs8[s] * wv.w;
            }
        }
    }
    if (o < O) {
        float4 bv = *(const float4*)&bias[o];
        #pragma unroll
        for (int s = 0; s < 8; s++) {
            float r[4] = {acc[s][0] + bv.x, acc[s][1] + bv.y, acc[s][2] + bv.z, acc[s][3] + bv.w};
            #pragma unroll
            for (int q = 0; q < 4; q++)
                r[q] = (act == 0) ? fmaxf(r[q], 0.f) : (1.f / (1.f + expf(-r[q])));
            *(float4*)&out[(size_t)(n0 + ns * 8 + s) * O + o] = make_float4(r[0], r[1], r[2], r[3]);
        }
    }
}

extern "C" void kernel_launch(void* const* d_in, const int* in_sizes, int n_in,
                              void* d_out, int out_size, void* d_ws, size_t ws_size,
                              hipStream_t stream)
{
    const float* x       = (const float*)d_in[0];
    const float* conv1_w = (const float*)d_in[1];
    const float* conv1_b = (const float*)d_in[2];
    const float* pconv_w = (const float*)d_in[3];
    const float* pconv_b = (const float*)d_in[4];
    const float* W_caps  = (const float*)d_in[5];
    const float* dec_w1  = (const float*)d_in[6];
    const float* dec_b1  = (const float*)d_in[7];
    const float* dec_w2  = (const float*)d_in[8];
    const float* dec_b2  = (const float*)d_in[9];
    const float* dec_w3  = (const float*)d_in[10];
    const float* dec_b3  = (const float*)d_in[11];
    float* out = (float*)d_out;

    float* ws = (float*)d_ws;
    size_t off = 0;
    auto alloc = [&](size_t nf) { float* p = ws + off; off += (nf + 63) & ~(size_t)63; return p; };
    unsigned short* xpack = (unsigned short*)alloc(26214400);  // 256*400*512 ushort
    unsigned short* wpack = (unsigned short*)alloc(5308416);   // 648*16*1024 ushort
    float* P    = alloc(2359296);     // pconv accumulation (256,9216)
    float* u_in = alloc(2359296);     // squashed (256,1152,8)
    float* bbuf = alloc(11520);       // routing logits b (1152,10)
    float* cbuf = alloc(11520);
    float* sbuf = alloc(4 * 40960);   // s partials (4 i-chunks)
    float* vbuf = alloc(40960);       // v (256,10,16)
    float* rin  = alloc(40960);       // masked decoder input (256,160)
    float* h1   = alloc(131072);
    float* h2   = alloc(262144);

    hipMemsetAsync(bbuf, 0, 11520 * sizeof(float), stream);
    hipMemsetAsync(P, 0, 2359296 * sizeof(float), stream);

    wpack_kernel<<<(648 * 16 * 64 + 255) / 256, 256, 0, stream>>>(pconv_w, wpack);
    conv1_kernel<<<dim3(256, 4), 256, 0, stream>>>(x, conv1_w, conv1_b, xpack);
    pconv_mfma_kernel<<<dim3(72, 2, 6), 256, 0, stream>>>(xpack, wpack, P);
    squash_u_kernel<<<1152, 256, 0, stream>>>(P, pconv_b, u_in);

    for (int r = 0; r < 4; ++r) {
        softmax_c_kernel<<<5, 256, 0, stream>>>(bbuf, cbuf);
        s_kernel<<<dim3(10, 16, 4), 256, 0, stream>>>(cbuf, u_in, W_caps, sbuf);
        squash_v_kernel<<<10, 256, 0, stream>>>(sbuf, vbuf, (r == 3) ? out : nullptr);
        if (r < 3) bupd_kernel<<<1152, 192, 0, stream>>>(u_in, vbuf, W_caps, bbuf);
    }

    mask_kernel<<<1, 256, 0, stream>>>(vbuf, rin);
    mlp_kernel<<<dim3(8, 2), 256, 0, stream>>>(rin, dec_w1, dec_b1, h1, 160, 512, 0);
    mlp_kernel<<<dim3(8, 4), 256, 0, stream>>>(h1, dec_w2, dec_b2, h2, 512, 1024, 0);
    mlp_kernel<<<dim3(8, 4), 256, 0, stream>>>(h2, dec_w3, dec_b3, out + 40960, 1024, 784, 1);
}

// Round 5
// 1636.298 us; speedup vs baseline: 4.5880x; 1.3135x over previous
//
#include <hip/hip_runtime.h>
#include <hip/hip_fp16.h>
#include <math.h>

// CapsNet forward. Round 5: pconv as blocked MFMA GEMM — M128xN256 tile,
// A double-buffered in LDS via global_load_lds (XOR-swizzled), B register-
// prefetched, kc=6 K-split with fp16 partials (no atomics).

typedef __attribute__((ext_vector_type(8))) short short8;
typedef __attribute__((ext_vector_type(4))) float floatx4;

__device__ __forceinline__ unsigned short bf16_rne(float f) {
    unsigned int u = __float_as_uint(f);
    return (unsigned short)((u + 0x7FFFu + ((u >> 16) & 1u)) >> 16);
}
__device__ __forceinline__ float bf16_tof(unsigned short h) {
    return __uint_as_float((unsigned int)h << 16);
}
__device__ __forceinline__ void load_lds16(const void* g, void* l) {
    __builtin_amdgcn_global_load_lds(
        (const __attribute__((address_space(1))) unsigned int*)g,
        (__attribute__((address_space(3))) unsigned int*)l, 16, 0, 0);
}

// ---------------- conv1: x(256,1,28,28) * w(256,81) -> xpack NHWC bf16 hi/lo ----------------
// xpack (ushort): [pix = n*400 + y*20 + x][2][256]  (hi plane 256, lo plane 256)
__global__ __launch_bounds__(256, 2) void conv1_kernel(
    const float* __restrict__ x, const float* __restrict__ w,
    const float* __restrict__ bias, unsigned short* __restrict__ xpack)
{
    __shared__ float xs[784];
    __shared__ float wl[64 * 81];
    int t = threadIdx.x;
    int n = blockIdx.x;
    int cot = blockIdx.y;

    for (int j = t; j < 784; j += 256) xs[j] = x[n * 784 + j];
    {
        int co_s = t >> 2, k0 = (t & 3) * 21;
        const float* wsrc = w + (size_t)(cot * 64 + co_s) * 81;
        #pragma unroll
        for (int k = 0; k < 21; ++k)
            if (k0 + k < 81) wl[co_s * 81 + k0 + k] = wsrc[k0 + k];
    }
    __syncthreads();

    int co_l = t & 63, slot = t >> 6;
    int co = cot * 64 + co_l;
    float bv = bias[co];
    for (int r5 = 0; r5 < 5; ++r5) {
        int py = slot * 5 + r5;
        float acc[20];
        #pragma unroll
        for (int i = 0; i < 20; i++) acc[i] = bv;
        #pragma unroll
        for (int ky = 0; ky < 9; ++ky) {
            float xr[28];
            const float4* rowp = (const float4*)&xs[(py + ky) * 28];
            #pragma unroll
            for (int q = 0; q < 7; q++) {
                float4 v4 = rowp[q];
                xr[4*q] = v4.x; xr[4*q+1] = v4.y; xr[4*q+2] = v4.z; xr[4*q+3] = v4.w;
            }
            #pragma unroll
            for (int kx = 0; kx < 9; ++kx) {
                float wv = wl[co_l * 81 + ky * 9 + kx];
                #pragma unroll
                for (int px = 0; px < 20; ++px) acc[px] += wv * xr[px + kx];
            }
        }
        #pragma unroll
        for (int px = 0; px < 20; ++px) {
            float v = acc[px];
            unsigned short h = bf16_rne(v);
            unsigned short l = bf16_rne(v - bf16_tof(h));
            size_t pix = (size_t)n * 400 + py * 20 + px;
            xpack[pix * 512 + co] = h;
            xpack[pix * 512 + 256 + co] = l;
        }
    }
}

// ---------------- weight repack: w[co][ci][9][9] -> frag-linear bf16 hi/lo ----------------
// wpack (ushort): [gs = kk*8+cb][g = co>>4][hi 512 | lo 512]
__global__ __launch_bounds__(256) void wpack_kernel(
    const float* __restrict__ w, unsigned short* __restrict__ wp)
{
    int tid = blockIdx.x * 256 + threadIdx.x;
    if (tid >= 648 * 16 * 64) return;
    int lane = tid & 63, g = (tid >> 6) & 15, gs = tid >> 10;
    int cb = gs & 7, kk = gs >> 3;
    int ky = kk / 9, kx = kk - ky * 9;
    int n16 = lane & 15, q = lane >> 4;
    int co = g * 16 + n16;
    unsigned short hi[8], lo[8];
    #pragma unroll
    for (int j = 0; j < 8; ++j) {
        int ci = cb * 32 + q * 8 + j;
        float v = w[((size_t)co * 256 + ci) * 81 + ky * 9 + kx];
        hi[j] = bf16_rne(v);
        lo[j] = bf16_rne(v - bf16_tof(hi[j]));
    }
    unsigned short* dst = wp + ((size_t)gs * 16 + g) * 1024 + lane * 8;
    *(short8*)dst         = *(short8*)hi;
    *(short8*)(dst + 512) = *(short8*)lo;
}

// ---------------- pconv GEMM: M=9216(m=n*36+pos) x N=256(co) x K=20736, 3-term bf16 ----
// grid (72 mtiles, 6 kc). Block 256 = 4 waves; wave w owns co [w*64, w*64+64).
// A: LDS double-buffer via global_load_lds (swizzled slots). B: register prefetch.
// Out: fp16 partials P6[kc][m][co], plain coalesced stores.
__global__ __launch_bounds__(256, 1) void pconv_mfma_kernel(
    const unsigned short* __restrict__ xp, const unsigned short* __restrict__ wp,
    __half* __restrict__ P6)
{
    __shared__ unsigned char lds[32768];        // 2 x 16KB A buffers
    int t = threadIdx.x;
    int lane = t & 63;
    int w = __builtin_amdgcn_readfirstlane(t >> 6);
    int mtile = blockIdx.x, kc = blockIdx.y;
    int m16 = lane & 15, q = lane >> 4;

    // A stage: wave w covers rows w*32..+32; instr j covers 8 rows (1024B).
    // Stored slot p of row r holds logical 16B-part (p ^ (r&7))  [XOR swizzle]
    unsigned int asrc[4];
    #pragma unroll
    for (int j = 0; j < 4; ++j) {
        int r = w * 32 + j * 8 + (lane >> 3);
        int m = mtile * 128 + r;
        int n = m / 36, pos = m - n * 36;
        int oy = pos / 6, ox = pos - oy * 6;
        int pixbase = n * 400 + oy * 40 + ox * 2;
        int pp = (lane & 7) ^ (lane >> 3);      // logical part this lane fetches
        int partoff = (pp < 4) ? pp * 16 : 512 + (pp - 4) * 16;
        asrc[j] = (unsigned int)(pixbase * 1024 + partoff);
    }
    const char* xb = (const char*)xp;
    const char* wb = (const char*)wp;

    floatx4 acc[8][4];
    #pragma unroll
    for (int a = 0; a < 8; ++a)
        #pragma unroll
        for (int b = 0; b < 4; ++b) acc[a][b] = (floatx4){0.f, 0.f, 0.f, 0.f};

    // frag-read slot offsets (swizzle inverse), constant per lane
    int slot_hi = (q ^ (m16 & 7)) * 16;
    int slot_lo = slot_hi ^ 64;

    auto stageA = [&](int s, int buf) {
        int gs = kc * 108 + s; if (gs > 647) gs = 647;
        int kk = gs >> 3, cb = gs & 7;
        int ky = kk / 9, kx = kk - ky * 9;
        unsigned int delta = (unsigned int)((ky * 20 + kx) * 1024 + cb * 64);
        #pragma unroll
        for (int j = 0; j < 4; ++j)
            load_lds16(xb + asrc[j] + delta,
                       (void*)(lds + buf * 16384 + w * 4096 + j * 1024));
    };
    auto loadB = [&](int s, short8* Bh, short8* Bl) {
        int gs = kc * 108 + s; if (gs > 647) gs = 647;
        #pragma unroll
        for (int c = 0; c < 4; ++c) {
            const char* bp = wb + ((size_t)gs * 16 + (w * 4 + c)) * 2048 + lane * 16;
            Bh[c] = *(const short8*)bp;
            Bl[c] = *(const short8*)(bp + 1024);
        }
    };
    auto compute = [&](int buf, short8* Bh, short8* Bl) {
        const char* base = (const char*)lds + buf * 16384 + m16 * 128;
        #pragma unroll
        for (int ms = 0; ms < 8; ++ms) {
            short8 Ah = *(const short8*)(base + ms * 2048 + slot_hi);
            short8 Al = *(const short8*)(base + ms * 2048 + slot_lo);
            #pragma unroll
            for (int c = 0; c < 4; ++c) {
                acc[ms][c] = __builtin_amdgcn_mfma_f32_16x16x32_bf16(Ah, Bh[c], acc[ms][c], 0, 0, 0);
                acc[ms][c] = __builtin_amdgcn_mfma_f32_16x16x32_bf16(Ah, Bl[c], acc[ms][c], 0, 0, 0);
                acc[ms][c] = __builtin_amdgcn_mfma_f32_16x16x32_bf16(Al, Bh[c], acc[ms][c], 0, 0, 0);
            }
        }
    };

    short8 Bh0[4], Bl0[4], Bh1[4], Bl1[4];
    stageA(0, 0);
    loadB(0, Bh0, Bl0);
    __syncthreads();                       // drains A(0)/B(0)
    for (int s = 0; s < 108; s += 2) {
        stageA(s + 1, 1);                  // async into buf1
        loadB(s + 1, Bh1, Bl1);            // in-flight across compute
        compute(0, Bh0, Bl0);
        __syncthreads();                   // drain (loads were issued early)
        stageA(s + 2, 0);
        loadB(s + 2, Bh0, Bl0);
        compute(1, Bh1, Bl1);
        __syncthreads();
    }

    // epilogue: C/D row=(lane>>4)*4+reg, col=lane&15. Store fp16 partials,
    // addr = ((kc*9216 + m)*256 + co); 4x64B full sectors per instr.
    __half* outp = P6 + ((size_t)kc * 9216 + (size_t)mtile * 128) * 256;
    #pragma unroll
    for (int ms = 0; ms < 8; ++ms)
        #pragma unroll
        for (int r = 0; r < 4; ++r) {
            int ml = ms * 16 + q * 4 + r;
            #pragma unroll
            for (int c = 0; c < 4; ++c) {
                int co = w * 64 + c * 16 + m16;
                outp[ml * 256 + co] = __float2half(acc[ms][c][r]);
            }
        }
}

// ---------------- reduce 6 fp16 kc-partials + bias + squash over 8-dim capsules ----------------
__global__ __launch_bounds__(256) void squash_u_kernel(
    const __half* __restrict__ P6, const float* __restrict__ pb, float* __restrict__ u)
{
    int cap = blockIdx.x * 256 + threadIdx.x;   // 0..294911
    int n = cap / 1152;
    int capl = cap - n * 1152;
    float z[8]; float n2 = 0.f;
    #pragma unroll
    for (int b = 0; b < 8; ++b) {
        int q2 = capl * 8 + b;                  // co*36 + pos
        int co = q2 / 36;
        int pos = q2 - co * 36;
        int m = n * 36 + pos;
        float s = 0.f;
        #pragma unroll
        for (int kc = 0; kc < 6; ++kc)
            s += __half2float(P6[((size_t)kc * 9216 + m) * 256 + co]);
        s += pb[co];
        z[b] = s; n2 += s * s;
    }
    float sc = sqrtf(n2) / (1.0f + n2);
    float4* op = (float4*)(u + (size_t)cap * 8);
    op[0] = make_float4(z[0]*sc, z[1]*sc, z[2]*sc, z[3]*sc);
    op[1] = make_float4(z[4]*sc, z[5]*sc, z[6]*sc, z[7]*sc);
}

// ---------------- softmax over j=10 ----------------
__global__ void softmax_c_kernel(const float* __restrict__ b, float* __restrict__ c)
{
    int i = blockIdx.x * 256 + threadIdx.x;
    if (i >= 1152) return;
    float e[10], m = -1e30f;
    #pragma unroll
    for (int j = 0; j < 10; j++) { e[j] = b[i * 10 + j]; m = fmaxf(m, e[j]); }
    float sum = 0.f;
    #pragma unroll
    for (int j = 0; j < 10; j++) { e[j] = expf(e[j] - m); sum += e[j]; }
    float inv = 1.f / sum;
    #pragma unroll
    for (int j = 0; j < 10; j++) c[i * 10 + j] = e[j] * inv;
}

// ---------------- s[n,j,a] partials over 8 i-chunks ----------------
__global__ __launch_bounds__(256) void s_kernel(
    const float* __restrict__ c, const float* __restrict__ u,
    const float* __restrict__ W, float* __restrict__ sbuf)
{
    int t = threadIdx.x;
    int a = t & 15, n_l = t >> 4;
    int j = blockIdx.x;
    int n = blockIdx.y * 16 + n_l;
    int i0 = blockIdx.z * 144;
    float acc = 0.f;
    #pragma unroll 4
    for (int i = i0; i < i0 + 144; ++i) {
        float cij = c[i * 10 + j];
        const float4* wpt = (const float4*)&W[(((size_t)i * 10 + j) * 16 + a) * 8];
        float4 w0 = wpt[0], w1 = wpt[1];
        const float4* up = (const float4*)&u[(size_t)n * 9216 + (size_t)i * 8];
        float4 q0 = up[0], q1 = up[1];
        float d = w0.x*q0.x + w0.y*q0.y + w0.z*q0.z + w0.w*q0.w
                + w1.x*q1.x + w1.y*q1.y + w1.z*q1.z + w1.w*q1.w;
        acc += cij * d;
    }
    sbuf[(size_t)blockIdx.z * 40960 + ((size_t)n * 10 + j) * 16 + a] = acc;
}

// ---------------- v = squash(sum of 8 s-partials) over 16-dim ----------------
__global__ void squash_v_kernel(const float* __restrict__ sbuf,
                                float* __restrict__ v, float* __restrict__ vout)
{
    int idx = blockIdx.x * 256 + threadIdx.x;
    if (idx >= 2560) return;
    float xv[16], n2 = 0.f;
    #pragma unroll
    for (int a = 0; a < 16; a++) {
        float s = 0.f;
        #pragma unroll
        for (int z = 0; z < 8; ++z) s += sbuf[z * 40960 + idx * 16 + a];
        xv[a] = s;
        n2 += s * s;
    }
    float sc = sqrtf(n2) / (1.0f + n2);
    #pragma unroll
    for (int a = 0; a < 16; a++) {
        float y = xv[a] * sc;
        v[idx * 16 + a] = y;
        if (vout) vout[idx * 16 + a] = y;
    }
}

// ---------------- b[i,j] += einsum, n split in 2 halves (atomic combine) ----------------
__global__ __launch_bounds__(192) void bupd_kernel(
    const float* __restrict__ u, const float* __restrict__ v,
    const float* __restrict__ W, float* __restrict__ b)
{
    int i = blockIdx.x;
    int n0 = blockIdx.y * 128;
    int t = threadIdx.x;
    if (t >= 160) return;
    int j = t >> 4, a = t & 15;
    float g[8];
    #pragma unroll
    for (int k = 0; k < 8; k++) g[k] = 0.f;
    #pragma unroll 4
    for (int n = n0; n < n0 + 128; ++n) {
        float vv = v[n * 160 + t];
        const float4* up = (const float4*)&u[(size_t)n * 9216 + (size_t)i * 8];
        float4 q0 = up[0], q1 = up[1];
        g[0] += q0.x * vv; g[1] += q0.y * vv; g[2] += q0.z * vv; g[3] += q0.w * vv;
        g[4] += q1.x * vv; g[5] += q1.y * vv; g[6] += q1.z * vv; g[7] += q1.w * vv;
    }
    const float4* wpt = (const float4*)&W[(((size_t)i * 10 + j) * 16 + a) * 8];
    float4 w0 = wpt[0], w1 = wpt[1];
    float p = w0.x*g[0] + w0.y*g[1] + w0.z*g[2] + w0.w*g[3]
            + w1.x*g[4] + w1.y*g[5] + w1.z*g[6] + w1.w*g[7];
    p += __shfl_xor(p, 1);
    p += __shfl_xor(p, 2);
    p += __shfl_xor(p, 4);
    p += __shfl_xor(p, 8);
    if (a == 0) atomicAdd(&b[i * 10 + j], p);
}

// ---------------- argmax(|v|) + mask -> decoder input (256,160) ----------------
__global__ void mask_kernel(const float* __restrict__ v, float* __restrict__ out)
{
    int n = threadIdx.x;
    const float* vp = &v[n * 160];
    int best = 0; float bestv = -1.f;
    for (int j = 0; j < 10; j++) {
        float n2 = 0.f;
        #pragma unroll
        for (int a = 0; a < 16; a++) { float y = vp[j * 16 + a]; n2 += y * y; }
        float ln = sqrtf(n2);
        if (ln > bestv) { bestv = ln; best = j; }
    }
    for (int j = 0; j < 10; j++)
        for (int a = 0; a < 16; a++)
            out[n * 160 + j * 16 + a] = (j == best) ? vp[j * 16 + a] : 0.f;
}

// ---------------- decoder GEMM: 16n x 256o per block ----------------
__global__ __launch_bounds__(256) void mlp_kernel(
    const float* __restrict__ X, const float* __restrict__ Wm,
    const float* __restrict__ bias, float* __restrict__ out,
    int K, int O, int act)
{
    __shared__ float XS[64 * 21];
    int t = threadIdx.x;
    int og = t & 63, ns = t >> 6;
    int n0 = blockIdx.x * 16;
    int o = blockIdx.y * 256 + og * 4;
    int o_c = min(o, O - 4);
    float acc[4][4] = {{0.f}};
    for (int kc = 0; kc < K; kc += 64) {
        int kn = min(64, K - kc);
        __syncthreads();
        {
            int k_l = t >> 2, nl = (t & 3) * 4;
            #pragma unroll
            for (int u2 = 0; u2 < 4; ++u2)
                XS[k_l * 21 + nl + u2] = (k_l < kn) ? X[(size_t)(n0 + nl + u2) * K + kc + k_l] : 0.f;
        }
        __syncthreads();
        for (int k = 0; k < kn; ++k) {
            float4 wv = *(const float4*)&Wm[(size_t)(kc + k) * O + o_c];
            float xs4[4];
            #pragma unroll
            for (int s2 = 0; s2 < 4; ++s2) xs4[s2] = XS[k * 21 + ns * 4 + s2];
            #pragma unroll
            for (int s2 = 0; s2 < 4; ++s2) {
                acc[s2][0] += xs4[s2] * wv.x;
                acc[s2][1] += xs4[s2] * wv.y;
                acc[s2][2] += xs4[s2] * wv.z;
                acc[s2][3] += xs4[s2] * wv.w;
            }
        }
    }
    if (o < O) {
        float4 bv = *(const float4*)&bias[o];
        #pragma unroll
        for (int s2 = 0; s2 < 4; ++s2) {
            float r[4] = {acc[s2][0] + bv.x, acc[s2][1] + bv.y, acc[s2][2] + bv.z, acc[s2][3] + bv.w};
            #pragma unroll
            for (int q = 0; q < 4; q++)
                r[q] = (act == 0) ? fmaxf(r[q], 0.f) : (1.f / (1.f + expf(-r[q])));
            *(float4*)&out[(size_t)(n0 + ns * 4 + s2) * O + o] = make_float4(r[0], r[1], r[2], r[3]);
        }
    }
}

extern "C" void kernel_launch(void* const* d_in, const int* in_sizes, int n_in,
                              void* d_out, int out_size, void* d_ws, size_t ws_size,
                              hipStream_t stream)
{
    const float* x       = (const float*)d_in[0];
    const float* conv1_w = (const float*)d_in[1];
    const float* conv1_b = (const float*)d_in[2];
    const float* pconv_w = (const float*)d_in[3];
    const float* pconv_b = (const float*)d_in[4];
    const float* W_caps  = (const float*)d_in[5];
    const float* dec_w1  = (const float*)d_in[6];
    const float* dec_b1  = (const float*)d_in[7];
    const float* dec_w2  = (const float*)d_in[8];
    const float* dec_b2  = (const float*)d_in[9];
    const float* dec_w3  = (const float*)d_in[10];
    const float* dec_b3  = (const float*)d_in[11];
    float* out = (float*)d_out;

    float* ws = (float*)d_ws;
    size_t off = 0;
    auto alloc = [&](size_t nf) { float* p = ws + off; off += (nf + 63) & ~(size_t)63; return p; };
    unsigned short* xpack = (unsigned short*)alloc(26214400);  // 256*400*512 ushort
    unsigned short* wpack = (unsigned short*)alloc(5308416);   // 648*16*1024 ushort
    __half* P6  = (__half*)alloc(7077888);   // 6*9216*256 fp16 partials
    float* u_in = alloc(2359296);
    float* bbuf = alloc(11520);
    float* cbuf = alloc(11520);
    float* sbuf = alloc(8 * 40960);
    float* vbuf = alloc(40960);
    float* rin  = alloc(40960);
    float* h1   = alloc(131072);
    float* h2   = alloc(262144);

    hipMemsetAsync(bbuf, 0, 11520 * sizeof(float), stream);

    wpack_kernel<<<(648 * 16 * 64 + 255) / 256, 256, 0, stream>>>(pconv_w, wpack);
    conv1_kernel<<<dim3(256, 4), 256, 0, stream>>>(x, conv1_w, conv1_b, xpack);
    pconv_mfma_kernel<<<dim3(72, 6), 256, 0, stream>>>(xpack, wpack, P6);
    squash_u_kernel<<<1152, 256, 0, stream>>>(P6, pconv_b, u_in);

    for (int r = 0; r < 4; ++r) {
        softmax_c_kernel<<<5, 256, 0, stream>>>(bbuf, cbuf);
        s_kernel<<<dim3(10, 16, 8), 256, 0, stream>>>(cbuf, u_in, W_caps, sbuf);
        squash_v_kernel<<<10, 256, 0, stream>>>(sbuf, vbuf, (r == 3) ? out : nullptr);
        if (r < 3) bupd_kernel<<<dim3(1152, 2), 192, 0, stream>>>(u_in, vbuf, W_caps, bbuf);
    }

    mask_kernel<<<1, 256, 0, stream>>>(vbuf, rin);
    mlp_kernel<<<dim3(16, 2), 256, 0, stream>>>(rin, dec_w1, dec_b1, h1, 160, 512, 0);
    mlp_kernel<<<dim3(16, 4), 256, 0, stream>>>(h1, dec_w2, dec_b2, h2, 512, 1024, 0);
    mlp_kernel<<<dim3(16, 4), 256, 0, stream>>>(h2, dec_w3, dec_b3, out + 40960, 1024, 784, 1);
}

// Round 6
// 1236.704 us; speedup vs baseline: 6.0705x; 1.3231x over previous
//
#include <hip/hip_runtime.h>
#include <hip/hip_fp16.h>
#include <math.h>

// CapsNet forward. Round 6: decoder MLP rewritten (templated K, K-split
// partials, unrolled batched loads); s_kernel retiled for W/u reuse
// (block = 32n x all-j x 24i, u read once per launch).

typedef __attribute__((ext_vector_type(8))) short short8;
typedef __attribute__((ext_vector_type(4))) float floatx4;

__device__ __forceinline__ unsigned short bf16_rne(float f) {
    unsigned int u = __float_as_uint(f);
    return (unsigned short)((u + 0x7FFFu + ((u >> 16) & 1u)) >> 16);
}
__device__ __forceinline__ float bf16_tof(unsigned short h) {
    return __uint_as_float((unsigned int)h << 16);
}
__device__ __forceinline__ void load_lds16(const void* g, void* l) {
    __builtin_amdgcn_global_load_lds(
        (const __attribute__((address_space(1))) unsigned int*)g,
        (__attribute__((address_space(3))) unsigned int*)l, 16, 0, 0);
}

// ---------------- conv1: x(256,1,28,28) * w(256,81) -> xpack NHWC bf16 hi/lo ----------------
__global__ __launch_bounds__(256, 2) void conv1_kernel(
    const float* __restrict__ x, const float* __restrict__ w,
    const float* __restrict__ bias, unsigned short* __restrict__ xpack)
{
    __shared__ float xs[784];
    __shared__ float wl[64 * 81];
    int t = threadIdx.x;
    int n = blockIdx.x;
    int cot = blockIdx.y;

    for (int j = t; j < 784; j += 256) xs[j] = x[n * 784 + j];
    {
        int co_s = t >> 2, k0 = (t & 3) * 21;
        const float* wsrc = w + (size_t)(cot * 64 + co_s) * 81;
        #pragma unroll
        for (int k = 0; k < 21; ++k)
            if (k0 + k < 81) wl[co_s * 81 + k0 + k] = wsrc[k0 + k];
    }
    __syncthreads();

    int co_l = t & 63, slot = t >> 6;
    int co = cot * 64 + co_l;
    float bv = bias[co];
    for (int r5 = 0; r5 < 5; ++r5) {
        int py = slot * 5 + r5;
        float acc[20];
        #pragma unroll
        for (int i = 0; i < 20; i++) acc[i] = bv;
        #pragma unroll
        for (int ky = 0; ky < 9; ++ky) {
            float xr[28];
            const float4* rowp = (const float4*)&xs[(py + ky) * 28];
            #pragma unroll
            for (int q = 0; q < 7; q++) {
                float4 v4 = rowp[q];
                xr[4*q] = v4.x; xr[4*q+1] = v4.y; xr[4*q+2] = v4.z; xr[4*q+3] = v4.w;
            }
            #pragma unroll
            for (int kx = 0; kx < 9; ++kx) {
                float wv = wl[co_l * 81 + ky * 9 + kx];
                #pragma unroll
                for (int px = 0; px < 20; ++px) acc[px] += wv * xr[px + kx];
            }
        }
        #pragma unroll
        for (int px = 0; px < 20; ++px) {
            float v = acc[px];
            unsigned short h = bf16_rne(v);
            unsigned short l = bf16_rne(v - bf16_tof(h));
            size_t pix = (size_t)n * 400 + py * 20 + px;
            xpack[pix * 512 + co] = h;
            xpack[pix * 512 + 256 + co] = l;
        }
    }
}

// ---------------- weight repack: w[co][ci][9][9] -> frag-linear bf16 hi/lo ----------------
__global__ __launch_bounds__(256) void wpack_kernel(
    const float* __restrict__ w, unsigned short* __restrict__ wp)
{
    int tid = blockIdx.x * 256 + threadIdx.x;
    if (tid >= 648 * 16 * 64) return;
    int lane = tid & 63, g = (tid >> 6) & 15, gs = tid >> 10;
    int cb = gs & 7, kk = gs >> 3;
    int ky = kk / 9, kx = kk - ky * 9;
    int n16 = lane & 15, q = lane >> 4;
    int co = g * 16 + n16;
    unsigned short hi[8], lo[8];
    #pragma unroll
    for (int j = 0; j < 8; ++j) {
        int ci = cb * 32 + q * 8 + j;
        float v = w[((size_t)co * 256 + ci) * 81 + ky * 9 + kx];
        hi[j] = bf16_rne(v);
        lo[j] = bf16_rne(v - bf16_tof(hi[j]));
    }
    unsigned short* dst = wp + ((size_t)gs * 16 + g) * 1024 + lane * 8;
    *(short8*)dst         = *(short8*)hi;
    *(short8*)(dst + 512) = *(short8*)lo;
}

// ---------------- pconv GEMM: M128 x N256 x K-split 6, 3-term bf16, LDS dbuf ----------------
__global__ __launch_bounds__(256, 1) void pconv_mfma_kernel(
    const unsigned short* __restrict__ xp, const unsigned short* __restrict__ wp,
    __half* __restrict__ P6)
{
    __shared__ unsigned char lds[32768];
    int t = threadIdx.x;
    int lane = t & 63;
    int w = __builtin_amdgcn_readfirstlane(t >> 6);
    int mtile = blockIdx.x, kc = blockIdx.y;
    int m16 = lane & 15, q = lane >> 4;

    unsigned int asrc[4];
    #pragma unroll
    for (int j = 0; j < 4; ++j) {
        int r = w * 32 + j * 8 + (lane >> 3);
        int m = mtile * 128 + r;
        int n = m / 36, pos = m - n * 36;
        int oy = pos / 6, ox = pos - oy * 6;
        int pixbase = n * 400 + oy * 40 + ox * 2;
        int pp = (lane & 7) ^ (lane >> 3);
        int partoff = (pp < 4) ? pp * 16 : 512 + (pp - 4) * 16;
        asrc[j] = (unsigned int)(pixbase * 1024 + partoff);
    }
    const char* xb = (const char*)xp;
    const char* wb = (const char*)wp;

    floatx4 acc[8][4];
    #pragma unroll
    for (int a = 0; a < 8; ++a)
        #pragma unroll
        for (int b = 0; b < 4; ++b) acc[a][b] = (floatx4){0.f, 0.f, 0.f, 0.f};

    int slot_hi = (q ^ (m16 & 7)) * 16;
    int slot_lo = slot_hi ^ 64;

    auto stageA = [&](int s, int buf) {
        int gs = kc * 108 + s; if (gs > 647) gs = 647;
        int kk = gs >> 3, cb = gs & 7;
        int ky = kk / 9, kx = kk - ky * 9;
        unsigned int delta = (unsigned int)((ky * 20 + kx) * 1024 + cb * 64);
        #pragma unroll
        for (int j = 0; j < 4; ++j)
            load_lds16(xb + asrc[j] + delta,
                       (void*)(lds + buf * 16384 + w * 4096 + j * 1024));
    };
    auto loadB = [&](int s, short8* Bh, short8* Bl) {
        int gs = kc * 108 + s; if (gs > 647) gs = 647;
        #pragma unroll
        for (int c = 0; c < 4; ++c) {
            const char* bp = wb + ((size_t)gs * 16 + (w * 4 + c)) * 2048 + lane * 16;
            Bh[c] = *(const short8*)bp;
            Bl[c] = *(const short8*)(bp + 1024);
        }
    };
    auto compute = [&](int buf, short8* Bh, short8* Bl) {
        const char* base = (const char*)lds + buf * 16384 + m16 * 128;
        #pragma unroll
        for (int ms = 0; ms < 8; ++ms) {
            short8 Ah = *(const short8*)(base + ms * 2048 + slot_hi);
            short8 Al = *(const short8*)(base + ms * 2048 + slot_lo);
            #pragma unroll
            for (int c = 0; c < 4; ++c) {
                acc[ms][c] = __builtin_amdgcn_mfma_f32_16x16x32_bf16(Ah, Bh[c], acc[ms][c], 0, 0, 0);
                acc[ms][c] = __builtin_amdgcn_mfma_f32_16x16x32_bf16(Ah, Bl[c], acc[ms][c], 0, 0, 0);
                acc[ms][c] = __builtin_amdgcn_mfma_f32_16x16x32_bf16(Al, Bh[c], acc[ms][c], 0, 0, 0);
            }
        }
    };

    short8 Bh0[4], Bl0[4], Bh1[4], Bl1[4];
    stageA(0, 0);
    loadB(0, Bh0, Bl0);
    __syncthreads();
    for (int s = 0; s < 108; s += 2) {
        stageA(s + 1, 1);
        loadB(s + 1, Bh1, Bl1);
        compute(0, Bh0, Bl0);
        __syncthreads();
        stageA(s + 2, 0);
        loadB(s + 2, Bh0, Bl0);
        compute(1, Bh1, Bl1);
        __syncthreads();
    }

    __half* outp = P6 + ((size_t)kc * 9216 + (size_t)mtile * 128) * 256;
    #pragma unroll
    for (int ms = 0; ms < 8; ++ms)
        #pragma unroll
        for (int r = 0; r < 4; ++r) {
            int ml = ms * 16 + q * 4 + r;
            #pragma unroll
            for (int c = 0; c < 4; ++c) {
                int co = w * 64 + c * 16 + m16;
                outp[ml * 256 + co] = __float2half(acc[ms][c][r]);
            }
        }
}

// ---------------- reduce 6 fp16 kc-partials + bias + squash over 8-dim capsules ----------------
__global__ __launch_bounds__(256) void squash_u_kernel(
    const __half* __restrict__ P6, const float* __restrict__ pb, float* __restrict__ u)
{
    int cap = blockIdx.x * 256 + threadIdx.x;
    int n = cap / 1152;
    int capl = cap - n * 1152;
    float z[8]; float n2 = 0.f;
    #pragma unroll
    for (int b = 0; b < 8; ++b) {
        int q2 = capl * 8 + b;
        int co = q2 / 36;
        int pos = q2 - co * 36;
        int m = n * 36 + pos;
        float s = 0.f;
        #pragma unroll
        for (int kc = 0; kc < 6; ++kc)
            s += __half2float(P6[((size_t)kc * 9216 + m) * 256 + co]);
        s += pb[co];
        z[b] = s; n2 += s * s;
    }
    float sc = sqrtf(n2) / (1.0f + n2);
    float4* op = (float4*)(u + (size_t)cap * 8);
    op[0] = make_float4(z[0]*sc, z[1]*sc, z[2]*sc, z[3]*sc);
    op[1] = make_float4(z[4]*sc, z[5]*sc, z[6]*sc, z[7]*sc);
}

// ---------------- softmax over j=10 ----------------
__global__ void softmax_c_kernel(const float* __restrict__ b, float* __restrict__ c)
{
    int i = blockIdx.x * 256 + threadIdx.x;
    if (i >= 1152) return;
    float e[10], m = -1e30f;
    #pragma unroll
    for (int j = 0; j < 10; j++) { e[j] = b[i * 10 + j]; m = fmaxf(m, e[j]); }
    float sum = 0.f;
    #pragma unroll
    for (int j = 0; j < 10; j++) { e[j] = expf(e[j] - m); sum += e[j]; }
    float inv = 1.f / sum;
    #pragma unroll
    for (int j = 0; j < 10; j++) c[i * 10 + j] = e[j] * inv;
}

// ---------------- s partials: block = (ntile of 32 n) x ALL j x (i-chunk 24) ----------------
// u read exactly once per launch; W re-read x8 (47 MB, L3-resident).
__global__ __launch_bounds__(256, 2) void s_kernel(
    const float* __restrict__ c, const float* __restrict__ u,
    const float* __restrict__ W, float* __restrict__ sbuf)
{
    int t = threadIdx.x;
    int a = t & 15, nl = t >> 4;
    int nt = blockIdx.x;                 // 0..7
    int bz = blockIdx.y;                 // 0..47
    int i0 = bz * 24;
    int n0 = nt * 32 + nl * 2;
    float acc[2][10];
    #pragma unroll
    for (int r = 0; r < 2; ++r)
        #pragma unroll
        for (int j = 0; j < 10; ++j) acc[r][j] = 0.f;

    for (int i = i0; i < i0 + 24; ++i) {
        const float* cb = &c[i * 10];
        float4 u0[2], u1[2];
        #pragma unroll
        for (int r = 0; r < 2; ++r) {
            const float4* up = (const float4*)&u[(size_t)(n0 + r) * 9216 + (size_t)i * 8];
            u0[r] = up[0]; u1[r] = up[1];
        }
        #pragma unroll
        for (int j = 0; j < 10; ++j) {
            const float4* wpt = (const float4*)&W[(((size_t)i * 10 + j) * 16 + a) * 8];
            float4 w0 = wpt[0], w1 = wpt[1];
            float cij = cb[j];
            #pragma unroll
            for (int r = 0; r < 2; ++r) {
                float d = w0.x*u0[r].x + w0.y*u0[r].y + w0.z*u0[r].z + w0.w*u0[r].w
                        + w1.x*u1[r].x + w1.y*u1[r].y + w1.z*u1[r].z + w1.w*u1[r].w;
                acc[r][j] += cij * d;
            }
        }
    }
    #pragma unroll
    for (int r = 0; r < 2; ++r)
        #pragma unroll
        for (int j = 0; j < 10; ++j)
            sbuf[(size_t)bz * 40960 + (((size_t)(n0 + r) * 10 + j) * 16) + a] = acc[r][j];
}

// ---------------- v = squash(sum of 48 s-partials) over 16-dim ----------------
__global__ void squash_v_kernel(const float* __restrict__ sbuf,
                                float* __restrict__ v, float* __restrict__ vout)
{
    int idx = blockIdx.x * 256 + threadIdx.x;
    if (idx >= 2560) return;
    float xv[16], n2 = 0.f;
    #pragma unroll
    for (int a = 0; a < 16; a++) {
        float s = 0.f;
        for (int z = 0; z < 48; ++z) s += sbuf[(size_t)z * 40960 + idx * 16 + a];
        xv[a] = s;
        n2 += s * s;
    }
    float sc = sqrtf(n2) / (1.0f + n2);
    #pragma unroll
    for (int a = 0; a < 16; a++) {
        float y = xv[a] * sc;
        v[idx * 16 + a] = y;
        if (vout) vout[idx * 16 + a] = y;
    }
}

// ---------------- b[i,j] += einsum, n split in 2 halves (atomic combine) ----------------
__global__ __launch_bounds__(192) void bupd_kernel(
    const float* __restrict__ u, const float* __restrict__ v,
    const float* __restrict__ W, float* __restrict__ b)
{
    int i = blockIdx.x;
    int n0 = blockIdx.y * 128;
    int t = threadIdx.x;
    if (t >= 160) return;
    int j = t >> 4, a = t & 15;
    float g[8];
    #pragma unroll
    for (int k = 0; k < 8; k++) g[k] = 0.f;
    #pragma unroll 4
    for (int n = n0; n < n0 + 128; ++n) {
        float vv = v[n * 160 + t];
        const float4* up = (const float4*)&u[(size_t)n * 9216 + (size_t)i * 8];
        float4 q0 = up[0], q1 = up[1];
        g[0] += q0.x * vv; g[1] += q0.y * vv; g[2] += q0.z * vv; g[3] += q0.w * vv;
        g[4] += q1.x * vv; g[5] += q1.y * vv; g[6] += q1.z * vv; g[7] += q1.w * vv;
    }
    const float4* wpt = (const float4*)&W[(((size_t)i * 10 + j) * 16 + a) * 8];
    float4 w0 = wpt[0], w1 = wpt[1];
    float p = w0.x*g[0] + w0.y*g[1] + w0.z*g[2] + w0.w*g[3]
            + w1.x*g[4] + w1.y*g[5] + w1.z*g[6] + w1.w*g[7];
    p += __shfl_xor(p, 1);
    p += __shfl_xor(p, 2);
    p += __shfl_xor(p, 4);
    p += __shfl_xor(p, 8);
    if (a == 0) atomicAdd(&b[i * 10 + j], p);
}

// ---------------- argmax(|v|) + mask -> decoder input (256,160) ----------------
__global__ void mask_kernel(const float* __restrict__ v, float* __restrict__ out)
{
    int n = threadIdx.x;
    const float* vp = &v[n * 160];
    int best = 0; float bestv = -1.f;
    for (int j = 0; j < 10; j++) {
        float n2 = 0.f;
        #pragma unroll
        for (int a = 0; a < 16; a++) { float y = vp[j * 16 + a]; n2 += y * y; }
        float ln = sqrtf(n2);
        if (ln > bestv) { bestv = ln; best = j; }
    }
    for (int j = 0; j < 10; j++)
        for (int a = 0; a < 16; a++)
            out[n * 160 + j * 16 + a] = (j == best) ? vp[j * 16 + a] : 0.f;
}

// ---------------- MLP partial: templated K, chunked; 16n x 256o per block ----------------
// partial[ks][n][O] += X[n][kc0:kc0+KCH] @ W[kc0:kc0+KCH][o]
template<int K, int KCH, int O>
__global__ __launch_bounds__(256, 2) void mlp_part_kernel(
    const float* __restrict__ X, const float* __restrict__ Wm,
    float* __restrict__ partial)
{
    __shared__ float XS[KCH * 16];              // [k][n], rows 64B
    int t = threadIdx.x;
    int og = t & 63, ns = t >> 6;
    int n0 = blockIdx.x * 16;
    int o = blockIdx.y * 256 + og * 4;
    int o_c = min(o, O - 4);
    int ks = blockIdx.z;
    int kc0 = ks * KCH;

    for (int idx = t; idx < KCH * 16; idx += 256) {
        int k_l = idx >> 4, n_l = idx & 15;
        XS[k_l * 16 + n_l] = X[(size_t)(n0 + n_l) * K + kc0 + k_l];
    }
    __syncthreads();

    float acc[4][4];
    #pragma unroll
    for (int r = 0; r < 4; ++r)
        #pragma unroll
        for (int q = 0; q < 4; ++q) acc[r][q] = 0.f;

    #pragma unroll 8
    for (int k = 0; k < KCH; ++k) {
        float4 wv = *(const float4*)&Wm[(size_t)(kc0 + k) * O + o_c];
        float4 xs4 = *(const float4*)&XS[k * 16 + ns * 4];
        acc[0][0] += xs4.x * wv.x; acc[0][1] += xs4.x * wv.y; acc[0][2] += xs4.x * wv.z; acc[0][3] += xs4.x * wv.w;
        acc[1][0] += xs4.y * wv.x; acc[1][1] += xs4.y * wv.y; acc[1][2] += xs4.y * wv.z; acc[1][3] += xs4.y * wv.w;
        acc[2][0] += xs4.z * wv.x; acc[2][1] += xs4.z * wv.y; acc[2][2] += xs4.z * wv.z; acc[2][3] += xs4.z * wv.w;
        acc[3][0] += xs4.w * wv.x; acc[3][1] += xs4.w * wv.y; acc[3][2] += xs4.w * wv.z; acc[3][3] += xs4.w * wv.w;
    }

    if (o < O) {
        float* pp = partial + ((size_t)ks * 256 + n0 + ns * 4) * O + o;
        #pragma unroll
        for (int r = 0; r < 4; ++r)
            *(float4*)(pp + (size_t)r * O) = make_float4(acc[r][0], acc[r][1], acc[r][2], acc[r][3]);
    }
}

// ---------------- MLP reduce: out[n][o] = act(sum_ks partial + bias) ----------------
template<int KS, int O, int ACT>
__global__ __launch_bounds__(256) void mlp_reduce_kernel(
    const float* __restrict__ partial, const float* __restrict__ bias,
    float* __restrict__ out)
{
    int n = blockIdx.y;
    int o = (blockIdx.x * 256 + threadIdx.x) * 4;
    if (o >= O) return;
    float4 s = make_float4(0.f, 0.f, 0.f, 0.f);
    #pragma unroll
    for (int ks = 0; ks < KS; ++ks) {
        float4 p = *(const float4*)&partial[((size_t)ks * 256 + n) * O + o];
        s.x += p.x; s.y += p.y; s.z += p.z; s.w += p.w;
    }
    float4 bv = *(const float4*)&bias[o];
    float r[4] = {s.x + bv.x, s.y + bv.y, s.z + bv.z, s.w + bv.w};
    #pragma unroll
    for (int q = 0; q < 4; ++q)
        r[q] = (ACT == 0) ? fmaxf(r[q], 0.f) : (1.f / (1.f + expf(-r[q])));
    *(float4*)&out[(size_t)n * O + o] = make_float4(r[0], r[1], r[2], r[3]);
}

extern "C" void kernel_launch(void* const* d_in, const int* in_sizes, int n_in,
                              void* d_out, int out_size, void* d_ws, size_t ws_size,
                              hipStream_t stream)
{
    const float* x       = (const float*)d_in[0];
    const float* conv1_w = (const float*)d_in[1];
    const float* conv1_b = (const float*)d_in[2];
    const float* pconv_w = (const float*)d_in[3];
    const float* pconv_b = (const float*)d_in[4];
    const float* W_caps  = (const float*)d_in[5];
    const float* dec_w1  = (const float*)d_in[6];
    const float* dec_b1  = (const float*)d_in[7];
    const float* dec_w2  = (const float*)d_in[8];
    const float* dec_b2  = (const float*)d_in[9];
    const float* dec_w3  = (const float*)d_in[10];
    const float* dec_b3  = (const float*)d_in[11];
    float* out = (float*)d_out;

    float* ws = (float*)d_ws;
    size_t off = 0;
    auto alloc = [&](size_t nf) { float* p = ws + off; off += (nf + 63) & ~(size_t)63; return p; };
    unsigned short* xpack = (unsigned short*)alloc(26214400);  // 256*400*512 ushort
    unsigned short* wpack = (unsigned short*)alloc(5308416);   // 648*16*1024 ushort
    __half* P6  = (__half*)alloc(7077888);   // 6*9216*256 fp16 partials
    float* u_in = alloc(2359296);
    float* bbuf = alloc(11520);
    float* cbuf = alloc(11520);
    float* sbuf = alloc(48 * 40960);
    float* vbuf = alloc(40960);
    float* rin  = alloc(40960);
    float* mpart = alloc(8 * 256 * 1024);    // MLP K-split partials (max layer)
    float* h1   = alloc(131072);
    float* h2   = alloc(262144);

    hipMemsetAsync(bbuf, 0, 11520 * sizeof(float), stream);

    wpack_kernel<<<(648 * 16 * 64 + 255) / 256, 256, 0, stream>>>(pconv_w, wpack);
    conv1_kernel<<<dim3(256, 4), 256, 0, stream>>>(x, conv1_w, conv1_b, xpack);
    pconv_mfma_kernel<<<dim3(72, 6), 256, 0, stream>>>(xpack, wpack, P6);
    squash_u_kernel<<<1152, 256, 0, stream>>>(P6, pconv_b, u_in);

    for (int r = 0; r < 4; ++r) {
        softmax_c_kernel<<<5, 256, 0, stream>>>(bbuf, cbuf);
        s_kernel<<<dim3(8, 48), 256, 0, stream>>>(cbuf, u_in, W_caps, sbuf);
        squash_v_kernel<<<10, 256, 0, stream>>>(sbuf, vbuf, (r == 3) ? out : nullptr);
        if (r < 3) bupd_kernel<<<dim3(1152, 2), 192, 0, stream>>>(u_in, vbuf, W_caps, bbuf);
    }

    mask_kernel<<<1, 256, 0, stream>>>(vbuf, rin);

    mlp_part_kernel<160, 80, 512><<<dim3(16, 2, 2), 256, 0, stream>>>(rin, dec_w1, mpart);
    mlp_reduce_kernel<2, 512, 0><<<dim3(1, 256), 256, 0, stream>>>(mpart, dec_b1, h1);
    mlp_part_kernel<512, 128, 1024><<<dim3(16, 4, 4), 256, 0, stream>>>(h1, dec_w2, mpart);
    mlp_reduce_kernel<4, 1024, 0><<<dim3(1, 256), 256, 0, stream>>>(mpart, dec_b2, h2);
    mlp_part_kernel<1024, 128, 784><<<dim3(16, 4, 8), 256, 0, stream>>>(h2, dec_w3, mpart);
    mlp_reduce_kernel<8, 784, 1><<<dim3(1, 256), 256, 0, stream>>>(mpart, dec_b3, out + 40960);
}

// Round 7
// 841.705 us; speedup vs baseline: 8.9193x; 1.4693x over previous
//
#include <hip/hip_runtime.h>
#include <hip/hip_fp16.h>
#include <math.h>

// CapsNet forward. Round 7: pconv 2-blocks/CU (M64 tile, 64 AGPR acc, kc=3),
// bupd i-tiled (v traffic /4), squash_v parallelized (160 blocks).

typedef __attribute__((ext_vector_type(8))) short short8;
typedef __attribute__((ext_vector_type(4))) float floatx4;

__device__ __forceinline__ unsigned short bf16_rne(float f) {
    unsigned int u = __float_as_uint(f);
    return (unsigned short)((u + 0x7FFFu + ((u >> 16) & 1u)) >> 16);
}
__device__ __forceinline__ float bf16_tof(unsigned short h) {
    return __uint_as_float((unsigned int)h << 16);
}
__device__ __forceinline__ void load_lds16(const void* g, void* l) {
    __builtin_amdgcn_global_load_lds(
        (const __attribute__((address_space(1))) unsigned int*)g,
        (__attribute__((address_space(3))) unsigned int*)l, 16, 0, 0);
}

// ---------------- conv1: x(256,1,28,28) * w(256,81) -> xpack NHWC bf16 hi/lo ----------------
__global__ __launch_bounds__(256, 2) void conv1_kernel(
    const float* __restrict__ x, const float* __restrict__ w,
    const float* __restrict__ bias, unsigned short* __restrict__ xpack)
{
    __shared__ float xs[784];
    __shared__ float wl[64 * 81];
    int t = threadIdx.x;
    int n = blockIdx.x;
    int cot = blockIdx.y;

    for (int j = t; j < 784; j += 256) xs[j] = x[n * 784 + j];
    {
        int co_s = t >> 2, k0 = (t & 3) * 21;
        const float* wsrc = w + (size_t)(cot * 64 + co_s) * 81;
        #pragma unroll
        for (int k = 0; k < 21; ++k)
            if (k0 + k < 81) wl[co_s * 81 + k0 + k] = wsrc[k0 + k];
    }
    __syncthreads();

    int co_l = t & 63, slot = t >> 6;
    int co = cot * 64 + co_l;
    float bv = bias[co];
    for (int r5 = 0; r5 < 5; ++r5) {
        int py = slot * 5 + r5;
        float acc[20];
        #pragma unroll
        for (int i = 0; i < 20; i++) acc[i] = bv;
        #pragma unroll
        for (int ky = 0; ky < 9; ++ky) {
            float xr[28];
            const float4* rowp = (const float4*)&xs[(py + ky) * 28];
            #pragma unroll
            for (int q = 0; q < 7; q++) {
                float4 v4 = rowp[q];
                xr[4*q] = v4.x; xr[4*q+1] = v4.y; xr[4*q+2] = v4.z; xr[4*q+3] = v4.w;
            }
            #pragma unroll
            for (int kx = 0; kx < 9; ++kx) {
                float wv = wl[co_l * 81 + ky * 9 + kx];
                #pragma unroll
                for (int px = 0; px < 20; ++px) acc[px] += wv * xr[px + kx];
            }
        }
        #pragma unroll
        for (int px = 0; px < 20; ++px) {
            float v = acc[px];
            unsigned short h = bf16_rne(v);
            unsigned short l = bf16_rne(v - bf16_tof(h));
            size_t pix = (size_t)n * 400 + py * 20 + px;
            xpack[pix * 512 + co] = h;
            xpack[pix * 512 + 256 + co] = l;
        }
    }
}

// ---------------- weight repack: w[co][ci][9][9] -> frag-linear bf16 hi/lo ----------------
__global__ __launch_bounds__(256) void wpack_kernel(
    const float* __restrict__ w, unsigned short* __restrict__ wp)
{
    int tid = blockIdx.x * 256 + threadIdx.x;
    if (tid >= 648 * 16 * 64) return;
    int lane = tid & 63, g = (tid >> 6) & 15, gs = tid >> 10;
    int cb = gs & 7, kk = gs >> 3;
    int ky = kk / 9, kx = kk - ky * 9;
    int n16 = lane & 15, q = lane >> 4;
    int co = g * 16 + n16;
    unsigned short hi[8], lo[8];
    #pragma unroll
    for (int j = 0; j < 8; ++j) {
        int ci = cb * 32 + q * 8 + j;
        float v = w[((size_t)co * 256 + ci) * 81 + ky * 9 + kx];
        hi[j] = bf16_rne(v);
        lo[j] = bf16_rne(v - bf16_tof(hi[j]));
    }
    unsigned short* dst = wp + ((size_t)gs * 16 + g) * 1024 + lane * 8;
    *(short8*)dst         = *(short8*)hi;
    *(short8*)(dst + 512) = *(short8*)lo;
}

// ---------------- pconv GEMM: M64 x N256 x kc-split 3, 3-term bf16, LDS dbuf ----------------
// 64 AGPR acc + ~128 VGPR -> 2 blocks/CU resident; 432 blocks all co-resident.
__global__ __launch_bounds__(256, 2) void pconv_mfma_kernel(
    const unsigned short* __restrict__ xp, const unsigned short* __restrict__ wp,
    __half* __restrict__ P3)
{
    __shared__ unsigned char lds[16384];        // 2 x 8KB A buffers
    int t = threadIdx.x;
    int lane = t & 63;
    int w = __builtin_amdgcn_readfirstlane(t >> 6);
    int mtile = blockIdx.x, kc = blockIdx.y;    // 144 mtiles of 64, 3 kc of 216 steps
    int m16 = lane & 15, q = lane >> 4;

    // A stage: wave w covers rows w*16..+16; instr j covers 8 rows (1KB).
    unsigned int asrc[2];
    #pragma unroll
    for (int j = 0; j < 2; ++j) {
        int r = w * 16 + j * 8 + (lane >> 3);
        int m = mtile * 64 + r;
        int n = m / 36, pos = m - n * 36;
        int oy = pos / 6, ox = pos - oy * 6;
        int pixbase = n * 400 + oy * 40 + ox * 2;
        int pp = (lane & 7) ^ (lane >> 3);      // XOR swizzle
        int partoff = (pp < 4) ? pp * 16 : 512 + (pp - 4) * 16;
        asrc[j] = (unsigned int)(pixbase * 1024 + partoff);
    }
    const char* xb = (const char*)xp;
    const char* wb = (const char*)wp;

    floatx4 acc[4][4];
    #pragma unroll
    for (int a = 0; a < 4; ++a)
        #pragma unroll
        for (int b = 0; b < 4; ++b) acc[a][b] = (floatx4){0.f, 0.f, 0.f, 0.f};

    int slot_hi = (q ^ (m16 & 7)) * 16;
    int slot_lo = slot_hi ^ 64;

    auto stageA = [&](int s, int buf) {
        int gs = kc * 216 + s; if (gs > 647) gs = 647;
        int kk = gs >> 3, cb = gs & 7;
        int ky = kk / 9, kx = kk - ky * 9;
        unsigned int delta = (unsigned int)((ky * 20 + kx) * 1024 + cb * 64);
        #pragma unroll
        for (int j = 0; j < 2; ++j)
            load_lds16(xb + asrc[j] + delta,
                       (void*)(lds + buf * 8192 + w * 2048 + j * 1024));
    };
    auto loadB = [&](int s, short8* Bh, short8* Bl) {
        int gs = kc * 216 + s; if (gs > 647) gs = 647;
        #pragma unroll
        for (int c = 0; c < 4; ++c) {
            const char* bp = wb + ((size_t)gs * 16 + (w * 4 + c)) * 2048 + lane * 16;
            Bh[c] = *(const short8*)bp;
            Bl[c] = *(const short8*)(bp + 1024);
        }
    };
    auto compute = [&](int buf, short8* Bh, short8* Bl) {
        #pragma unroll
        for (int ms = 0; ms < 4; ++ms) {
            const char* base = (const char*)lds + buf * 8192 + (ms * 16 + m16) * 128;
            short8 Ah = *(const short8*)(base + slot_hi);
            short8 Al = *(const short8*)(base + slot_lo);
            #pragma unroll
            for (int c = 0; c < 4; ++c) {
                acc[ms][c] = __builtin_amdgcn_mfma_f32_16x16x32_bf16(Ah, Bh[c], acc[ms][c], 0, 0, 0);
                acc[ms][c] = __builtin_amdgcn_mfma_f32_16x16x32_bf16(Ah, Bl[c], acc[ms][c], 0, 0, 0);
                acc[ms][c] = __builtin_amdgcn_mfma_f32_16x16x32_bf16(Al, Bh[c], acc[ms][c], 0, 0, 0);
            }
        }
    };

    short8 Bh0[4], Bl0[4], Bh1[4], Bl1[4];
    stageA(0, 0);
    loadB(0, Bh0, Bl0);
    __syncthreads();
    for (int s = 0; s < 216; s += 2) {
        stageA(s + 1, 1);
        loadB(s + 1, Bh1, Bl1);
        compute(0, Bh0, Bl0);
        __syncthreads();
        stageA(s + 2, 0);
        loadB(s + 2, Bh0, Bl0);
        compute(1, Bh1, Bl1);
        __syncthreads();
    }

    // epilogue: C/D row=(lane>>4)*4+reg, col=lane&15 -> fp16 partials
    __half* outp = P3 + ((size_t)kc * 9216 + (size_t)mtile * 64) * 256;
    #pragma unroll
    for (int ms = 0; ms < 4; ++ms)
        #pragma unroll
        for (int r = 0; r < 4; ++r) {
            int ml = ms * 16 + q * 4 + r;
            #pragma unroll
            for (int c = 0; c < 4; ++c) {
                int co = w * 64 + c * 16 + m16;
                outp[ml * 256 + co] = __float2half(acc[ms][c][r]);
            }
        }
}

// ---------------- reduce 3 fp16 kc-partials + bias + squash over 8-dim capsules ----------------
__global__ __launch_bounds__(256) void squash_u_kernel(
    const __half* __restrict__ P3, const float* __restrict__ pb, float* __restrict__ u)
{
    int cap = blockIdx.x * 256 + threadIdx.x;
    int n = cap / 1152;
    int capl = cap - n * 1152;
    float z[8]; float n2 = 0.f;
    #pragma unroll
    for (int b = 0; b < 8; ++b) {
        int q2 = capl * 8 + b;
        int co = q2 / 36;
        int pos = q2 - co * 36;
        int m = n * 36 + pos;
        float s = 0.f;
        #pragma unroll
        for (int kc = 0; kc < 3; ++kc)
            s += __half2float(P3[((size_t)kc * 9216 + m) * 256 + co]);
        s += pb[co];
        z[b] = s; n2 += s * s;
    }
    float sc = sqrtf(n2) / (1.0f + n2);
    float4* op = (float4*)(u + (size_t)cap * 8);
    op[0] = make_float4(z[0]*sc, z[1]*sc, z[2]*sc, z[3]*sc);
    op[1] = make_float4(z[4]*sc, z[5]*sc, z[6]*sc, z[7]*sc);
}

// ---------------- softmax over j=10 ----------------
__global__ void softmax_c_kernel(const float* __restrict__ b, float* __restrict__ c)
{
    int i = blockIdx.x * 256 + threadIdx.x;
    if (i >= 1152) return;
    float e[10], m = -1e30f;
    #pragma unroll
    for (int j = 0; j < 10; j++) { e[j] = b[i * 10 + j]; m = fmaxf(m, e[j]); }
    float sum = 0.f;
    #pragma unroll
    for (int j = 0; j < 10; j++) { e[j] = expf(e[j] - m); sum += e[j]; }
    float inv = 1.f / sum;
    #pragma unroll
    for (int j = 0; j < 10; j++) c[i * 10 + j] = e[j] * inv;
}

// ---------------- s partials: block = (ntile of 32 n) x ALL j x (i-chunk 24) ----------------
__global__ __launch_bounds__(256, 2) void s_kernel(
    const float* __restrict__ c, const float* __restrict__ u,
    const float* __restrict__ W, float* __restrict__ sbuf)
{
    int t = threadIdx.x;
    int a = t & 15, nl = t >> 4;
    int nt = blockIdx.x;                 // 0..7
    int bz = blockIdx.y;                 // 0..47
    int i0 = bz * 24;
    int n0 = nt * 32 + nl * 2;
    float acc[2][10];
    #pragma unroll
    for (int r = 0; r < 2; ++r)
        #pragma unroll
        for (int j = 0; j < 10; ++j) acc[r][j] = 0.f;

    for (int i = i0; i < i0 + 24; ++i) {
        const float* cb = &c[i * 10];
        float4 u0[2], u1[2];
        #pragma unroll
        for (int r = 0; r < 2; ++r) {
            const float4* up = (const float4*)&u[(size_t)(n0 + r) * 9216 + (size_t)i * 8];
            u0[r] = up[0]; u1[r] = up[1];
        }
        #pragma unroll
        for (int j = 0; j < 10; ++j) {
            const float4* wpt = (const float4*)&W[(((size_t)i * 10 + j) * 16 + a) * 8];
            float4 w0 = wpt[0], w1 = wpt[1];
            float cij = cb[j];
            #pragma unroll
            for (int r = 0; r < 2; ++r) {
                float d = w0.x*u0[r].x + w0.y*u0[r].y + w0.z*u0[r].z + w0.w*u0[r].w
                        + w1.x*u1[r].x + w1.y*u1[r].y + w1.z*u1[r].z + w1.w*u1[r].w;
                acc[r][j] += cij * d;
            }
        }
    }
    #pragma unroll
    for (int r = 0; r < 2; ++r)
        #pragma unroll
        for (int j = 0; j < 10; ++j)
            sbuf[(size_t)bz * 40960 + (((size_t)(n0 + r) * 10 + j) * 16) + a] = acc[r][j];
}

// ---------------- v = squash(sum of 48 s-partials); 160 blocks, shfl norm ----------------
__global__ __launch_bounds__(256) void squash_v_kernel(const float* __restrict__ sbuf,
                                float* __restrict__ v, float* __restrict__ vout)
{
    int t = threadIdx.x;
    int a = t & 15;
    int idx = blockIdx.x * 16 + (t >> 4);        // (n*10+j) in 0..2559
    float s = 0.f;
    #pragma unroll
    for (int z = 0; z < 48; ++z) s += sbuf[(size_t)z * 40960 + idx * 16 + a];
    float n2 = s * s;
    n2 += __shfl_xor(n2, 1);
    n2 += __shfl_xor(n2, 2);
    n2 += __shfl_xor(n2, 4);
    n2 += __shfl_xor(n2, 8);
    float sc = sqrtf(n2) / (1.0f + n2);
    float y = s * sc;
    v[idx * 16 + a] = y;
    if (vout) vout[idx * 16 + a] = y;
}

// ---------------- b[i,j] update, i-tile of 4 per block (v traffic /4) ----------------
__global__ __launch_bounds__(192) void bupd_kernel(
    const float* __restrict__ u, const float* __restrict__ v,
    const float* __restrict__ W, float* __restrict__ b)
{
    int i0 = blockIdx.x * 4;             // 288 i-groups
    int n0 = blockIdx.y * 128;           // 2 n-halves
    int t = threadIdx.x;
    if (t >= 160) return;
    int j = t >> 4, a = t & 15;
    float g4[4][8];
    #pragma unroll
    for (int g = 0; g < 4; ++g)
        #pragma unroll
        for (int k = 0; k < 8; ++k) g4[g][k] = 0.f;

    for (int n = n0; n < n0 + 128; ++n) {
        float vv = v[n * 160 + t];                            // coalesced
        const float4* ub = (const float4*)&u[(size_t)n * 9216 + (size_t)i0 * 8];  // uniform
        #pragma unroll
        for (int g = 0; g < 4; ++g) {
            float4 q0 = ub[g * 2], q1 = ub[g * 2 + 1];
            g4[g][0] += q0.x * vv; g4[g][1] += q0.y * vv; g4[g][2] += q0.z * vv; g4[g][3] += q0.w * vv;
            g4[g][4] += q1.x * vv; g4[g][5] += q1.y * vv; g4[g][6] += q1.z * vv; g4[g][7] += q1.w * vv;
        }
    }
    #pragma unroll
    for (int g = 0; g < 4; ++g) {
        int i = i0 + g;
        const float4* wpt = (const float4*)&W[(((size_t)i * 10 + j) * 16 + a) * 8];
        float4 w0 = wpt[0], w1 = wpt[1];
        float p = w0.x*g4[g][0] + w0.y*g4[g][1] + w0.z*g4[g][2] + w0.w*g4[g][3]
                + w1.x*g4[g][4] + w1.y*g4[g][5] + w1.z*g4[g][6] + w1.w*g4[g][7];
        p += __shfl_xor(p, 1);
        p += __shfl_xor(p, 2);
        p += __shfl_xor(p, 4);
        p += __shfl_xor(p, 8);
        if (a == 0) atomicAdd(&b[i * 10 + j], p);
    }
}

// ---------------- argmax(|v|) + mask -> decoder input (256,160) ----------------
__global__ void mask_kernel(const float* __restrict__ v, float* __restrict__ out)
{
    int n = threadIdx.x;
    const float* vp = &v[n * 160];
    int best = 0; float bestv = -1.f;
    for (int j = 0; j < 10; j++) {
        float n2 = 0.f;
        #pragma unroll
        for (int a = 0; a < 16; a++) { float y = vp[j * 16 + a]; n2 += y * y; }
        float ln = sqrtf(n2);
        if (ln > bestv) { bestv = ln; best = j; }
    }
    for (int j = 0; j < 10; j++)
        for (int a = 0; a < 16; a++)
            out[n * 160 + j * 16 + a] = (j == best) ? vp[j * 16 + a] : 0.f;
}

// ---------------- MLP partial: templated K, chunked; 16n x 256o per block ----------------
template<int K, int KCH, int O>
__global__ __launch_bounds__(256, 2) void mlp_part_kernel(
    const float* __restrict__ X, const float* __restrict__ Wm,
    float* __restrict__ partial)
{
    __shared__ float XS[KCH * 16];
    int t = threadIdx.x;
    int og = t & 63, ns = t >> 6;
    int n0 = blockIdx.x * 16;
    int o = blockIdx.y * 256 + og * 4;
    int o_c = min(o, O - 4);
    int ks = blockIdx.z;
    int kc0 = ks * KCH;

    for (int idx = t; idx < KCH * 16; idx += 256) {
        int k_l = idx >> 4, n_l = idx & 15;
        XS[k_l * 16 + n_l] = X[(size_t)(n0 + n_l) * K + kc0 + k_l];
    }
    __syncthreads();

    float acc[4][4];
    #pragma unroll
    for (int r = 0; r < 4; ++r)
        #pragma unroll
        for (int q = 0; q < 4; ++q) acc[r][q] = 0.f;

    #pragma unroll 8
    for (int k = 0; k < KCH; ++k) {
        float4 wv = *(const float4*)&Wm[(size_t)(kc0 + k) * O + o_c];
        float4 xs4 = *(const float4*)&XS[k * 16 + ns * 4];
        acc[0][0] += xs4.x * wv.x; acc[0][1] += xs4.x * wv.y; acc[0][2] += xs4.x * wv.z; acc[0][3] += xs4.x * wv.w;
        acc[1][0] += xs4.y * wv.x; acc[1][1] += xs4.y * wv.y; acc[1][2] += xs4.y * wv.z; acc[1][3] += xs4.y * wv.w;
        acc[2][0] += xs4.z * wv.x; acc[2][1] += xs4.z * wv.y; acc[2][2] += xs4.z * wv.z; acc[2][3] += xs4.z * wv.w;
        acc[3][0] += xs4.w * wv.x; acc[3][1] += xs4.w * wv.y; acc[3][2] += xs4.w * wv.z; acc[3][3] += xs4.w * wv.w;
    }

    if (o < O) {
        float* pp = partial + ((size_t)ks * 256 + n0 + ns * 4) * O + o;
        #pragma unroll
        for (int r = 0; r < 4; ++r)
            *(float4*)(pp + (size_t)r * O) = make_float4(acc[r][0], acc[r][1], acc[r][2], acc[r][3]);
    }
}

// ---------------- MLP reduce: out[n][o] = act(sum_ks partial + bias) ----------------
template<int KS, int O, int ACT>
__global__ __launch_bounds__(256) void mlp_reduce_kernel(
    const float* __restrict__ partial, const float* __restrict__ bias,
    float* __restrict__ out)
{
    int n = blockIdx.y;
    int o = (blockIdx.x * 256 + threadIdx.x) * 4;
    if (o >= O) return;
    float4 s = make_float4(0.f, 0.f, 0.f, 0.f);
    #pragma unroll
    for (int ks = 0; ks < KS; ++ks) {
        float4 p = *(const float4*)&partial[((size_t)ks * 256 + n) * O + o];
        s.x += p.x; s.y += p.y; s.z += p.z; s.w += p.w;
    }
    float4 bv = *(const float4*)&bias[o];
    float r[4] = {s.x + bv.x, s.y + bv.y, s.z + bv.z, s.w + bv.w};
    #pragma unroll
    for (int q = 0; q < 4; ++q)
        r[q] = (ACT == 0) ? fmaxf(r[q], 0.f) : (1.f / (1.f + expf(-r[q])));
    *(float4*)&out[(size_t)n * O + o] = make_float4(r[0], r[1], r[2], r[3]);
}

extern "C" void kernel_launch(void* const* d_in, const int* in_sizes, int n_in,
                              void* d_out, int out_size, void* d_ws, size_t ws_size,
                              hipStream_t stream)
{
    const float* x       = (const float*)d_in[0];
    const float* conv1_w = (const float*)d_in[1];
    const float* conv1_b = (const float*)d_in[2];
    const float* pconv_w = (const float*)d_in[3];
    const float* pconv_b = (const float*)d_in[4];
    const float* W_caps  = (const float*)d_in[5];
    const float* dec_w1  = (const float*)d_in[6];
    const float* dec_b1  = (const float*)d_in[7];
    const float* dec_w2  = (const float*)d_in[8];
    const float* dec_b2  = (const float*)d_in[9];
    const float* dec_w3  = (const float*)d_in[10];
    const float* dec_b3  = (const float*)d_in[11];
    float* out = (float*)d_out;

    float* ws = (float*)d_ws;
    size_t off = 0;
    auto alloc = [&](size_t nf) { float* p = ws + off; off += (nf + 63) & ~(size_t)63; return p; };
    unsigned short* xpack = (unsigned short*)alloc(26214400);  // 256*400*512 ushort
    unsigned short* wpack = (unsigned short*)alloc(5308416);   // 648*16*1024 ushort
    __half* P3  = (__half*)alloc(3538944);   // 3*9216*256 fp16 partials
    float* u_in = alloc(2359296);
    float* bbuf = alloc(11520);
    float* cbuf = alloc(11520);
    float* sbuf = alloc(48 * 40960);
    float* vbuf = alloc(40960);
    float* rin  = alloc(40960);
    float* mpart = alloc(8 * 256 * 1024);
    float* h1   = alloc(131072);
    float* h2   = alloc(262144);

    hipMemsetAsync(bbuf, 0, 11520 * sizeof(float), stream);

    wpack_kernel<<<(648 * 16 * 64 + 255) / 256, 256, 0, stream>>>(pconv_w, wpack);
    conv1_kernel<<<dim3(256, 4), 256, 0, stream>>>(x, conv1_w, conv1_b, xpack);
    pconv_mfma_kernel<<<dim3(144, 3), 256, 0, stream>>>(xpack, wpack, P3);
    squash_u_kernel<<<1152, 256, 0, stream>>>(P3, pconv_b, u_in);

    for (int r = 0; r < 4; ++r) {
        softmax_c_kernel<<<5, 256, 0, stream>>>(bbuf, cbuf);
        s_kernel<<<dim3(8, 48), 256, 0, stream>>>(cbuf, u_in, W_caps, sbuf);
        squash_v_kernel<<<160, 256, 0, stream>>>(sbuf, vbuf, (r == 3) ? out : nullptr);
        if (r < 3) bupd_kernel<<<dim3(288, 2), 192, 0, stream>>>(u_in, vbuf, W_caps, bbuf);
    }

    mask_kernel<<<1, 256, 0, stream>>>(vbuf, rin);

    mlp_part_kernel<160, 80, 512><<<dim3(16, 2, 2), 256, 0, stream>>>(rin, dec_w1, mpart);
    mlp_reduce_kernel<2, 512, 0><<<dim3(1, 256), 256, 0, stream>>>(mpart, dec_b1, h1);
    mlp_part_kernel<512, 128, 1024><<<dim3(16, 4, 4), 256, 0, stream>>>(h1, dec_w2, mpart);
    mlp_reduce_kernel<4, 1024, 0><<<dim3(1, 256), 256, 0, stream>>>(mpart, dec_b2, h2);
    mlp_part_kernel<1024, 128, 784><<<dim3(16, 4, 8), 256, 0, stream>>>(h2, dec_w3, mpart);
    mlp_reduce_kernel<8, 784, 1><<<dim3(1, 256), 256, 0, stream>>>(mpart, dec_b3, out + 40960);
}

// Round 8
// 763.618 us; speedup vs baseline: 9.8313x; 1.1023x over previous
//
#include <hip/hip_runtime.h>
#include <hip/hip_fp16.h>
#include <math.h>

// CapsNet forward. Round 8: pconv 2-term fp16 MFMA (A=hi+lo fp16, B=single fp16,
// 33% less MFMA work, half the B traffic), BK=64 double-gs barriers; softmax
// fused into s_kernel.

typedef __attribute__((ext_vector_type(8))) _Float16 half8;
typedef __attribute__((ext_vector_type(8))) short short8;
typedef __attribute__((ext_vector_type(4))) float floatx4;

__device__ __forceinline__ unsigned short f16bits(float v) {
    _Float16 h = (_Float16)v;
    unsigned short b;
    __builtin_memcpy(&b, &h, 2);
    return b;
}
__device__ __forceinline__ float f16back(unsigned short b) {
    _Float16 h;
    __builtin_memcpy(&h, &b, 2);
    return (float)h;
}
__device__ __forceinline__ void load_lds16(const void* g, void* l) {
    __builtin_amdgcn_global_load_lds(
        (const __attribute__((address_space(1))) unsigned int*)g,
        (__attribute__((address_space(3))) unsigned int*)l, 16, 0, 0);
}

// ---------------- conv1: x(256,1,28,28) * w(256,81) -> xpack NHWC fp16 hi/lo ----------------
// xpack (ushort): [pix = n*400 + y*20 + x][hi 256 | lo 256]
__global__ __launch_bounds__(256, 2) void conv1_kernel(
    const float* __restrict__ x, const float* __restrict__ w,
    const float* __restrict__ bias, unsigned short* __restrict__ xpack)
{
    __shared__ float xs[784];
    __shared__ float wl[64 * 81];
    int t = threadIdx.x;
    int n = blockIdx.x;
    int cot = blockIdx.y;

    for (int j = t; j < 784; j += 256) xs[j] = x[n * 784 + j];
    {
        int co_s = t >> 2, k0 = (t & 3) * 21;
        const float* wsrc = w + (size_t)(cot * 64 + co_s) * 81;
        #pragma unroll
        for (int k = 0; k < 21; ++k)
            if (k0 + k < 81) wl[co_s * 81 + k0 + k] = wsrc[k0 + k];
    }
    __syncthreads();

    int co_l = t & 63, slot = t >> 6;
    int co = cot * 64 + co_l;
    float bv = bias[co];
    for (int r5 = 0; r5 < 5; ++r5) {
        int py = slot * 5 + r5;
        float acc[20];
        #pragma unroll
        for (int i = 0; i < 20; i++) acc[i] = bv;
        #pragma unroll
        for (int ky = 0; ky < 9; ++ky) {
            float xr[28];
            const float4* rowp = (const float4*)&xs[(py + ky) * 28];
            #pragma unroll
            for (int q = 0; q < 7; q++) {
                float4 v4 = rowp[q];
                xr[4*q] = v4.x; xr[4*q+1] = v4.y; xr[4*q+2] = v4.z; xr[4*q+3] = v4.w;
            }
            #pragma unroll
            for (int kx = 0; kx < 9; ++kx) {
                float wv = wl[co_l * 81 + ky * 9 + kx];
                #pragma unroll
                for (int px = 0; px < 20; ++px) acc[px] += wv * xr[px + kx];
            }
        }
        #pragma unroll
        for (int px = 0; px < 20; ++px) {
            float v = acc[px];
            unsigned short h = f16bits(v);
            unsigned short l = f16bits(v - f16back(h));
            size_t pix = (size_t)n * 400 + py * 20 + px;
            xpack[pix * 512 + co] = h;
            xpack[pix * 512 + 256 + co] = l;
        }
    }
}

// ---------------- weight repack: w[co][ci][9][9] -> frag-linear single fp16 ----------------
// wpack (ushort): [gs = kk*8+cb][g = co>>4][512]
__global__ __launch_bounds__(256) void wpack_kernel(
    const float* __restrict__ w, unsigned short* __restrict__ wp)
{
    int tid = blockIdx.x * 256 + threadIdx.x;
    if (tid >= 648 * 16 * 64) return;
    int lane = tid & 63, g = (tid >> 6) & 15, gs = tid >> 10;
    int cb = gs & 7, kk = gs >> 3;
    int ky = kk / 9, kx = kk - ky * 9;
    int n16 = lane & 15, q = lane >> 4;
    int co = g * 16 + n16;
    unsigned short hv[8];
    #pragma unroll
    for (int j = 0; j < 8; ++j) {
        int ci = cb * 32 + q * 8 + j;
        hv[j] = f16bits(w[((size_t)co * 256 + ci) * 81 + ky * 9 + kx]);
    }
    unsigned short* dst = wp + ((size_t)gs * 16 + g) * 512 + lane * 8;
    *(short8*)dst = *(short8*)hv;
}

// ---------------- pconv GEMM: M64 x N256 x kc-split 3, 2-term fp16, BK=64 dbuf ----------------
// acc 64 AGPR + ~120 VGPR -> 2 blocks/CU. 108 barriers/kernel, 64 MFMA/wave/barrier.
__global__ __launch_bounds__(256, 2) void pconv_mfma_kernel(
    const unsigned short* __restrict__ xp, const unsigned short* __restrict__ wp,
    __half* __restrict__ P3)
{
    __shared__ unsigned char lds[32768];        // 2 bufs x (2 gs x 8KB)
    int t = threadIdx.x;
    int lane = t & 63;
    int w = __builtin_amdgcn_readfirstlane(t >> 6);
    int mtile = blockIdx.x, kc = blockIdx.y;    // 144 mtiles of 64 rows, 3 kc of 216 gs
    int m16 = lane & 15, q = lane >> 4;

    unsigned int asrc[2];                        // j=0,1 -> 8 rows each
    #pragma unroll
    for (int j = 0; j < 2; ++j) {
        int r = w * 16 + j * 8 + (lane >> 3);
        int m = mtile * 64 + r;
        int n = m / 36, pos = m - n * 36;
        int oy = pos / 6, ox = pos - oy * 6;
        int pixbase = n * 400 + oy * 40 + ox * 2;
        int pp = (lane & 7) ^ (lane >> 3);       // XOR swizzle
        int partoff = (pp < 4) ? pp * 16 : 512 + (pp - 4) * 16;
        asrc[j] = (unsigned int)(pixbase * 1024 + partoff);
    }
    const char* xb = (const char*)xp;
    const char* wb = (const char*)wp;

    floatx4 acc[4][4];
    #pragma unroll
    for (int a = 0; a < 4; ++a)
        #pragma unroll
        for (int b = 0; b < 4; ++b) acc[a][b] = (floatx4){0.f, 0.f, 0.f, 0.f};

    int slot_hi = (q ^ (m16 & 7)) * 16;
    int slot_lo = slot_hi ^ 64;

    // stage pair p (gs 2p, 2p+1) into buffer buf
    auto stageP = [&](int p, int buf) {
        #pragma unroll
        for (int e = 0; e < 2; ++e) {
            int s = 2 * p + e; if (s > 215) s = 215;
            int gs = kc * 216 + s;
            int kk = gs >> 3, cb = gs & 7;
            int ky = kk / 9, kx = kk - ky * 9;
            unsigned int delta = (unsigned int)((ky * 20 + kx) * 1024 + cb * 64);
            #pragma unroll
            for (int j = 0; j < 2; ++j)
                load_lds16(xb + asrc[j] + delta,
                           (void*)(lds + buf * 16384 + e * 8192 + w * 2048 + j * 1024));
        }
    };
    auto loadB = [&](int s, half8* B) {
        if (s > 215) s = 215;
        int gs = kc * 216 + s;
        #pragma unroll
        for (int c = 0; c < 4; ++c)
            B[c] = *(const half8*)(wb + ((size_t)gs * 16 + (w * 4 + c)) * 1024 + lane * 16);
    };
    auto compute = [&](int buf, int e, half8* B) {
        #pragma unroll
        for (int ms = 0; ms < 4; ++ms) {
            const char* base = (const char*)lds + buf * 16384 + e * 8192 + (ms * 16 + m16) * 128;
            half8 Ah = *(const half8*)(base + slot_hi);
            half8 Al = *(const half8*)(base + slot_lo);
            #pragma unroll
            for (int c = 0; c < 4; ++c) {
                acc[ms][c] = __builtin_amdgcn_mfma_f32_16x16x32_f16(Ah, B[c], acc[ms][c], 0, 0, 0);
                acc[ms][c] = __builtin_amdgcn_mfma_f32_16x16x32_f16(Al, B[c], acc[ms][c], 0, 0, 0);
            }
        }
    };

    half8 Bcur[4], Bnext[4];
    stageP(0, 0);
    loadB(0, Bcur);
    __syncthreads();
    for (int p = 0; p < 108; ++p) {
        int buf = p & 1;
        stageP(p + 1, buf ^ 1);          // async LDS stage of next pair
        loadB(2 * p + 1, Bnext);
        compute(buf, 0, Bcur);           // 32 MFMA; Bnext/stage in flight
        loadB(2 * p + 2, Bcur);          // next pair's first gs
        compute(buf, 1, Bnext);          // 32 MFMA
        __syncthreads();                  // drains stage(p+1) + Bcur (issued 32 MFMA ago)
    }

    // epilogue: C/D row=(lane>>4)*4+reg, col=lane&15 -> fp16 partials [kc][m][co]
    __half* outp = P3 + ((size_t)kc * 9216 + (size_t)mtile * 64) * 256;
    #pragma unroll
    for (int ms = 0; ms < 4; ++ms)
        #pragma unroll
        for (int r = 0; r < 4; ++r) {
            int ml = ms * 16 + q * 4 + r;
            #pragma unroll
            for (int c = 0; c < 4; ++c) {
                int co = w * 64 + c * 16 + m16;
                outp[ml * 256 + co] = __float2half(acc[ms][c][r]);
            }
        }
}

// ---------------- reduce 3 fp16 kc-partials + bias + squash over 8-dim capsules ----------------
__global__ __launch_bounds__(256) void squash_u_kernel(
    const __half* __restrict__ P3, const float* __restrict__ pb, float* __restrict__ u)
{
    int cap = blockIdx.x * 256 + threadIdx.x;
    int n = cap / 1152;
    int capl = cap - n * 1152;
    float z[8]; float n2 = 0.f;
    #pragma unroll
    for (int b = 0; b < 8; ++b) {
        int q2 = capl * 8 + b;
        int co = q2 / 36;
        int pos = q2 - co * 36;
        int m = n * 36 + pos;
        float s = 0.f;
        #pragma unroll
        for (int kc = 0; kc < 3; ++kc)
            s += __half2float(P3[((size_t)kc * 9216 + m) * 256 + co]);
        s += pb[co];
        z[b] = s; n2 += s * s;
    }
    float sc = sqrtf(n2) / (1.0f + n2);
    float4* op = (float4*)(u + (size_t)cap * 8);
    op[0] = make_float4(z[0]*sc, z[1]*sc, z[2]*sc, z[3]*sc);
    op[1] = make_float4(z[4]*sc, z[5]*sc, z[6]*sc, z[7]*sc);
}

// ---------------- s partials with fused softmax: block = 32n x ALL j x 24i ----------------
__global__ __launch_bounds__(256, 2) void s_kernel(
    const float* __restrict__ b, const float* __restrict__ u,
    const float* __restrict__ W, float* __restrict__ sbuf)
{
    __shared__ float cs[24][10];
    int t = threadIdx.x;
    int a = t & 15, nl = t >> 4;
    int nt = blockIdx.x;                 // 0..7
    int bz = blockIdx.y;                 // 0..47
    int i0 = bz * 24;
    int n0 = nt * 32 + nl * 2;

    if (t < 24) {                        // softmax over j for this block's i rows
        int i = i0 + t;
        float e[10], m = -1e30f;
        #pragma unroll
        for (int j = 0; j < 10; j++) { e[j] = b[i * 10 + j]; m = fmaxf(m, e[j]); }
        float sum = 0.f;
        #pragma unroll
        for (int j = 0; j < 10; j++) { e[j] = expf(e[j] - m); sum += e[j]; }
        float inv = 1.f / sum;
        #pragma unroll
        for (int j = 0; j < 10; j++) cs[t][j] = e[j] * inv;
    }
    __syncthreads();

    float acc[2][10];
    #pragma unroll
    for (int r = 0; r < 2; ++r)
        #pragma unroll
        for (int j = 0; j < 10; ++j) acc[r][j] = 0.f;

    for (int i = i0; i < i0 + 24; ++i) {
        float4 u0[2], u1[2];
        #pragma unroll
        for (int r = 0; r < 2; ++r) {
            const float4* up = (const float4*)&u[(size_t)(n0 + r) * 9216 + (size_t)i * 8];
            u0[r] = up[0]; u1[r] = up[1];
        }
        #pragma unroll
        for (int j = 0; j < 10; ++j) {
            const float4* wpt = (const float4*)&W[(((size_t)i * 10 + j) * 16 + a) * 8];
            float4 w0 = wpt[0], w1 = wpt[1];
            float cij = cs[i - i0][j];
            #pragma unroll
            for (int r = 0; r < 2; ++r) {
                float d = w0.x*u0[r].x + w0.y*u0[r].y + w0.z*u0[r].z + w0.w*u0[r].w
                        + w1.x*u1[r].x + w1.y*u1[r].y + w1.z*u1[r].z + w1.w*u1[r].w;
                acc[r][j] += cij * d;
            }
        }
    }
    #pragma unroll
    for (int r = 0; r < 2; ++r)
        #pragma unroll
        for (int j = 0; j < 10; ++j)
            sbuf[(size_t)bz * 40960 + (((size_t)(n0 + r) * 10 + j) * 16) + a] = acc[r][j];
}

// ---------------- v = squash(sum of 48 s-partials); 160 blocks, shfl norm ----------------
__global__ __launch_bounds__(256) void squash_v_kernel(const float* __restrict__ sbuf,
                                float* __restrict__ v, float* __restrict__ vout)
{
    int t = threadIdx.x;
    int a = t & 15;
    int idx = blockIdx.x * 16 + (t >> 4);        // (n*10+j) in 0..2559
    float s = 0.f;
    #pragma unroll
    for (int z = 0; z < 48; ++z) s += sbuf[(size_t)z * 40960 + idx * 16 + a];
    float n2 = s * s;
    n2 += __shfl_xor(n2, 1);
    n2 += __shfl_xor(n2, 2);
    n2 += __shfl_xor(n2, 4);
    n2 += __shfl_xor(n2, 8);
    float sc = sqrtf(n2) / (1.0f + n2);
    float y = s * sc;
    v[idx * 16 + a] = y;
    if (vout) vout[idx * 16 + a] = y;
}

// ---------------- b[i,j] update, i-tile of 4 per block ----------------
__global__ __launch_bounds__(192) void bupd_kernel(
    const float* __restrict__ u, const float* __restrict__ v,
    const float* __restrict__ W, float* __restrict__ b)
{
    int i0 = blockIdx.x * 4;             // 288 i-groups
    int n0 = blockIdx.y * 128;           // 2 n-halves
    int t = threadIdx.x;
    if (t >= 160) return;
    int j = t >> 4, a = t & 15;
    float g4[4][8];
    #pragma unroll
    for (int g = 0; g < 4; ++g)
        #pragma unroll
        for (int k = 0; k < 8; ++k) g4[g][k] = 0.f;

    for (int n = n0; n < n0 + 128; ++n) {
        float vv = v[n * 160 + t];                            // coalesced
        const float4* ub = (const float4*)&u[(size_t)n * 9216 + (size_t)i0 * 8];  // uniform
        #pragma unroll
        for (int g = 0; g < 4; ++g) {
            float4 q0 = ub[g * 2], q1 = ub[g * 2 + 1];
            g4[g][0] += q0.x * vv; g4[g][1] += q0.y * vv; g4[g][2] += q0.z * vv; g4[g][3] += q0.w * vv;
            g4[g][4] += q1.x * vv; g4[g][5] += q1.y * vv; g4[g][6] += q1.z * vv; g4[g][7] += q1.w * vv;
        }
    }
    #pragma unroll
    for (int g = 0; g < 4; ++g) {
        int i = i0 + g;
        const float4* wpt = (const float4*)&W[(((size_t)i * 10 + j) * 16 + a) * 8];
        float4 w0 = wpt[0], w1 = wpt[1];
        float p = w0.x*g4[g][0] + w0.y*g4[g][1] + w0.z*g4[g][2] + w0.w*g4[g][3]
                + w1.x*g4[g][4] + w1.y*g4[g][5] + w1.z*g4[g][6] + w1.w*g4[g][7];
        p += __shfl_xor(p, 1);
        p += __shfl_xor(p, 2);
        p += __shfl_xor(p, 4);
        p += __shfl_xor(p, 8);
        if (a == 0) atomicAdd(&b[i * 10 + j], p);
    }
}

// ---------------- argmax(|v|) + mask -> decoder input (256,160) ----------------
__global__ void mask_kernel(const float* __restrict__ v, float* __restrict__ out)
{
    int n = threadIdx.x;
    const float* vp = &v[n * 160];
    int best = 0; float bestv = -1.f;
    for (int j = 0; j < 10; j++) {
        float n2 = 0.f;
        #pragma unroll
        for (int a = 0; a < 16; a++) { float y = vp[j * 16 + a]; n2 += y * y; }
        float ln = sqrtf(n2);
        if (ln > bestv) { bestv = ln; best = j; }
    }
    for (int j = 0; j < 10; j++)
        for (int a = 0; a < 16; a++)
            out[n * 160 + j * 16 + a] = (j == best) ? vp[j * 16 + a] : 0.f;
}

// ---------------- MLP partial: templated K, chunked; 16n x 256o per block ----------------
template<int K, int KCH, int O>
__global__ __launch_bounds__(256, 2) void mlp_part_kernel(
    const float* __restrict__ X, const float* __restrict__ Wm,
    float* __restrict__ partial)
{
    __shared__ float XS[KCH * 16];
    int t = threadIdx.x;
    int og = t & 63, ns = t >> 6;
    int n0 = blockIdx.x * 16;
    int o = blockIdx.y * 256 + og * 4;
    int o_c = min(o, O - 4);
    int ks = blockIdx.z;
    int kc0 = ks * KCH;

    for (int idx = t; idx < KCH * 16; idx += 256) {
        int k_l = idx >> 4, n_l = idx & 15;
        XS[k_l * 16 + n_l] = X[(size_t)(n0 + n_l) * K + kc0 + k_l];
    }
    __syncthreads();

    float acc[4][4];
    #pragma unroll
    for (int r = 0; r < 4; ++r)
        #pragma unroll
        for (int q = 0; q < 4; ++q) acc[r][q] = 0.f;

    #pragma unroll 8
    for (int k = 0; k < KCH; ++k) {
        float4 wv = *(const float4*)&Wm[(size_t)(kc0 + k) * O + o_c];
        float4 xs4 = *(const float4*)&XS[k * 16 + ns * 4];
        acc[0][0] += xs4.x * wv.x; acc[0][1] += xs4.x * wv.y; acc[0][2] += xs4.x * wv.z; acc[0][3] += xs4.x * wv.w;
        acc[1][0] += xs4.y * wv.x; acc[1][1] += xs4.y * wv.y; acc[1][2] += xs4.y * wv.z; acc[1][3] += xs4.y * wv.w;
        acc[2][0] += xs4.z * wv.x; acc[2][1] += xs4.z * wv.y; acc[2][2] += xs4.z * wv.z; acc[2][3] += xs4.z * wv.w;
        acc[3][0] += xs4.w * wv.x; acc[3][1] += xs4.w * wv.y; acc[3][2] += xs4.w * wv.z; acc[3][3] += xs4.w * wv.w;
    }

    if (o < O) {
        float* pp = partial + ((size_t)ks * 256 + n0 + ns * 4) * O + o;
        #pragma unroll
        for (int r = 0; r < 4; ++r)
            *(float4*)(pp + (size_t)r * O) = make_float4(acc[r][0], acc[r][1], acc[r][2], acc[r][3]);
    }
}

// ---------------- MLP reduce: out[n][o] = act(sum_ks partial + bias) ----------------
template<int KS, int O, int ACT>
__global__ __launch_bounds__(256) void mlp_reduce_kernel(
    const float* __restrict__ partial, const float* __restrict__ bias,
    float* __restrict__ out)
{
    int n = blockIdx.y;
    int o = (blockIdx.x * 256 + threadIdx.x) * 4;
    if (o >= O) return;
    float4 s = make_float4(0.f, 0.f, 0.f, 0.f);
    #pragma unroll
    for (int ks = 0; ks < KS; ++ks) {
        float4 p = *(const float4*)&partial[((size_t)ks * 256 + n) * O + o];
        s.x += p.x; s.y += p.y; s.z += p.z; s.w += p.w;
    }
    float4 bv = *(const float4*)&bias[o];
    float r[4] = {s.x + bv.x, s.y + bv.y, s.z + bv.z, s.w + bv.w};
    #pragma unroll
    for (int q = 0; q < 4; ++q)
        r[q] = (ACT == 0) ? fmaxf(r[q], 0.f) : (1.f / (1.f + expf(-r[q])));
    *(float4*)&out[(size_t)n * O + o] = make_float4(r[0], r[1], r[2], r[3]);
}

extern "C" void kernel_launch(void* const* d_in, const int* in_sizes, int n_in,
                              void* d_out, int out_size, void* d_ws, size_t ws_size,
                              hipStream_t stream)
{
    const float* x       = (const float*)d_in[0];
    const float* conv1_w = (const float*)d_in[1];
    const float* conv1_b = (const float*)d_in[2];
    const float* pconv_w = (const float*)d_in[3];
    const float* pconv_b = (const float*)d_in[4];
    const float* W_caps  = (const float*)d_in[5];
    const float* dec_w1  = (const float*)d_in[6];
    const float* dec_b1  = (const float*)d_in[7];
    const float* dec_w2  = (const float*)d_in[8];
    const float* dec_b2  = (const float*)d_in[9];
    const float* dec_w3  = (const float*)d_in[10];
    const float* dec_b3  = (const float*)d_in[11];
    float* out = (float*)d_out;

    float* ws = (float*)d_ws;
    size_t off = 0;
    auto alloc = [&](size_t nf) { float* p = ws + off; off += (nf + 63) & ~(size_t)63; return p; };
    unsigned short* xpack = (unsigned short*)alloc(26214400);  // 256*400*512 ushort
    unsigned short* wpack = (unsigned short*)alloc(2654208);   // 648*16*512 ushort
    __half* P3  = (__half*)alloc(3538944);   // 3*9216*256 fp16 partials
    float* u_in = alloc(2359296);
    float* bbuf = alloc(11520);
    float* sbuf = alloc(48 * 40960);
    float* vbuf = alloc(40960);
    float* rin  = alloc(40960);
    float* mpart = alloc(8 * 256 * 1024);
    float* h1   = alloc(131072);
    float* h2   = alloc(262144);

    hipMemsetAsync(bbuf, 0, 11520 * sizeof(float), stream);

    wpack_kernel<<<(648 * 16 * 64 + 255) / 256, 256, 0, stream>>>(pconv_w, wpack);
    conv1_kernel<<<dim3(256, 4), 256, 0, stream>>>(x, conv1_w, conv1_b, xpack);
    pconv_mfma_kernel<<<dim3(144, 3), 256, 0, stream>>>(xpack, wpack, P3);
    squash_u_kernel<<<1152, 256, 0, stream>>>(P3, pconv_b, u_in);

    for (int r = 0; r < 4; ++r) {
        s_kernel<<<dim3(8, 48), 256, 0, stream>>>(bbuf, u_in, W_caps, sbuf);
        squash_v_kernel<<<160, 256, 0, stream>>>(sbuf, vbuf, (r == 3) ? out : nullptr);
        if (r < 3) bupd_kernel<<<dim3(288, 2), 192, 0, stream>>>(u_in, vbuf, W_caps, bbuf);
    }

    mask_kernel<<<1, 256, 0, stream>>>(vbuf, rin);

    mlp_part_kernel<160, 80, 512><<<dim3(16, 2, 2), 256, 0, stream>>>(rin, dec_w1, mpart);
    mlp_reduce_kernel<2, 512, 0><<<dim3(1, 256), 256, 0, stream>>>(mpart, dec_b1, h1);
    mlp_part_kernel<512, 128, 1024><<<dim3(16, 4, 4), 256, 0, stream>>>(h1, dec_w2, mpart);
    mlp_reduce_kernel<4, 1024, 0><<<dim3(1, 256), 256, 0, stream>>>(mpart, dec_b2, h2);
    mlp_part_kernel<1024, 128, 784><<<dim3(16, 4, 8), 256, 0, stream>>>(h2, dec_w3, mpart);
    mlp_reduce_kernel<8, 784, 1><<<dim3(1, 256), 256, 0, stream>>>(mpart, dec_b3, out + 40960);
}